// Round 4
// baseline (1943.468 us; speedup 1.0000x reference)
//
#include <hip/hip_runtime.h>

typedef __attribute__((ext_vector_type(8))) short bt8;   // 8 bf16 (4 VGPR)
typedef __attribute__((ext_vector_type(4))) float f32x4; // 4 f32

__device__ __forceinline__ ushort f2bf(float f) {
    union { float f; unsigned int i; } v; v.f = f;
    unsigned int r = v.i + 0x7fffu + ((v.i >> 16) & 1u);
    return (ushort)(r >> 16);
}

// ---------------- f32 -> bf16 elementwise convert
__global__ __launch_bounds__(256) void cvt_bf16(const float* __restrict__ in,
                                                ushort* __restrict__ out, int n) {
    int i = blockIdx.x * 256 + threadIdx.x;
    if (i < n) out[i] = f2bf(in[i]);
}

// ---------------- weight transpose+convert: W[768,768] f32 (in,out) -> WT[768,768] bf16 (out,in)
__global__ void transpose768(const float* __restrict__ W, ushort* __restrict__ WT) {
    __shared__ float t[32][33];
    int bx = blockIdx.x * 32, by = blockIdx.y * 32;
    int x = threadIdx.x, y0 = threadIdx.y;
    for (int y = y0; y < 32; y += 8)
        t[y][x] = W[(size_t)(by + y) * 768 + bx + x];
    __syncthreads();
    for (int y = y0; y < 32; y += 8)
        WT[(size_t)(bx + y) * 768 + by + x] = f2bf(t[x][y]);
}

// ---------------- MFMA bf16 GEMM: C[M,N] f32 = A[M,K] bf16 @ BT[N,K]^T bf16
#define BM 128
#define BN 128
#define BKK 32
#define LDT 40  // halfword stride (32 + 8 pad)

__global__ __launch_bounds__(256) void gemm_bt(
    const ushort* __restrict__ A, const ushort* __restrict__ BT,
    float* __restrict__ C, int M, int N, int K)
{
    __shared__ ushort As[BM][LDT];
    __shared__ ushort Bs[BN][LDT];
    const int tid = threadIdx.x;
    const int row0 = blockIdx.x * BM, col0 = blockIdx.y * BN;
    const int wave = tid >> 6, lane = tid & 63;
    const int wm = (wave >> 1) * 64, wn = (wave & 1) * 64;
    const int lr = lane & 15, lk = (lane >> 4) * 8;
    const int sr = tid >> 2;          // staging row 0..63
    const int sc = (tid & 3) * 8;     // staging col (halfwords)

    f32x4 acc[4][4];
    for (int mi = 0; mi < 4; ++mi)
        for (int ni = 0; ni < 4; ++ni)
            acc[mi][ni] = (f32x4){0.f, 0.f, 0.f, 0.f};

    for (int kt = 0; kt < K; kt += BKK) {
        __syncthreads();
        for (int rr = sr; rr < BM; rr += 64) {
            int gr = row0 + rr;
            int4 av; av.x = av.y = av.z = av.w = 0;
            if (gr < M) av = *(const int4*)(A + (size_t)gr * K + kt + sc);
            *(int4*)&As[rr][sc] = av;
            int gc = col0 + rr;
            int4 bv; bv.x = bv.y = bv.z = bv.w = 0;
            if (gc < N) bv = *(const int4*)(BT + (size_t)gc * K + kt + sc);
            *(int4*)&Bs[rr][sc] = bv;
        }
        __syncthreads();
        bt8 af[4], bf[4];
        for (int mi = 0; mi < 4; ++mi)
            af[mi] = *(const bt8*)&As[wm + mi * 16 + lr][lk];
        for (int ni = 0; ni < 4; ++ni)
            bf[ni] = *(const bt8*)&Bs[wn + ni * 16 + lr][lk];
        for (int mi = 0; mi < 4; ++mi)
            for (int ni = 0; ni < 4; ++ni)
                acc[mi][ni] = __builtin_amdgcn_mfma_f32_16x16x32_bf16(
                    af[mi], bf[ni], acc[mi][ni], 0, 0, 0);
    }

    for (int mi = 0; mi < 4; ++mi) {
        int orow0 = row0 + wm + mi * 16 + (lane >> 4) * 4;
        for (int ni = 0; ni < 4; ++ni) {
            int ocol = col0 + wn + ni * 16 + lr;
            if (ocol >= N) continue;
            for (int r2 = 0; r2 < 4; ++r2) {
                int orow = orow0 + r2;
                if (orow < M) C[(size_t)orow * N + ocol] = acc[mi][ni][r2];
            }
        }
    }
}

// ---------------- per-(b) column sums of rk, rv over R=97 rows
__global__ void relsum(const float* __restrict__ rk, const float* __restrict__ rv,
                       float* __restrict__ rks, float* __restrict__ rvs) {
    int b = blockIdx.x;
    int c = blockIdx.y * 256 + threadIdx.x;  // 0..767
    float s1 = 0.f, s2 = 0.f;
    for (int r = 0; r < 97; ++r) {
        s1 += rk[(size_t)(b * 97 + r) * 768 + c];
        s2 += rv[(size_t)(b * 97 + r) * 768 + c];
    }
    rks[b * 768 + c] = s1;
    rvs[b * 768 + c] = s2;
}

// ---------------- doc-doc flash attention (fused_k = k + rksum, fused_v = v + rvsum)
#define LPAD 68

__global__ __launch_bounds__(64) void attn_doc(
    const float* __restrict__ qb, const float* __restrict__ kb, const float* __restrict__ vb,
    const float* __restrict__ ksum, const float* __restrict__ vsum,
    const int* __restrict__ mask, ushort* __restrict__ psi)
{
    __shared__ float smK[64][LPAD];
    __shared__ float smV[64][LPAD];
    __shared__ float madd[64];
    const int tid = threadIdx.x;
    const int bh = blockIdx.x, b = bh / 12, h = bh % 12;
    const int i0 = blockIdx.y * 64;
    const size_t base = (size_t)b * 1024 * 768 + h * 64;
    const float ks = ksum[b * 768 + h * 64 + tid];
    const float vs = vsum[b * 768 + h * 64 + tid];

    // stage Q block (coalesced), then scatter to per-thread registers
    for (int r = 0; r < 64; ++r)
        smK[r][tid] = qb[base + (size_t)(i0 + r) * 768 + tid];
    __syncthreads();
    float q[64];
    {
        const float4* qr = (const float4*)&smK[tid][0];
        #pragma unroll
        for (int d4 = 0; d4 < 16; ++d4) {
            float4 v = qr[d4];
            q[4*d4+0] = v.x; q[4*d4+1] = v.y; q[4*d4+2] = v.z; q[4*d4+3] = v.w;
        }
    }
    float m = -3.0e38f, l = 0.f;
    float o[64];
    #pragma unroll
    for (int d = 0; d < 64; ++d) o[d] = 0.f;

    for (int jt = 0; jt < 16; ++jt) {
        __syncthreads();
        const int j0 = jt * 64;
        for (int r = 0; r < 64; ++r) {
            smK[r][tid] = kb[base + (size_t)(j0 + r) * 768 + tid] + ks;
            smV[r][tid] = vb[base + (size_t)(j0 + r) * 768 + tid] + vs;
        }
        madd[tid] = (mask[b * 1024 + j0 + tid] == 0) ? -1e30f : 0.f;
        __syncthreads();
        for (int j = 0; j < 64; ++j) {
            const float4* kr = (const float4*)&smK[j][0];
            float s = 0.f;
            #pragma unroll
            for (int d4 = 0; d4 < 16; ++d4) {
                float4 kv = kr[d4];
                s += q[4*d4+0]*kv.x + q[4*d4+1]*kv.y + q[4*d4+2]*kv.z + q[4*d4+3]*kv.w;
            }
            s = s * 0.125f + madd[j];
            if (s > m) {
                float corr = __expf(m - s);
                l *= corr;
                #pragma unroll
                for (int d = 0; d < 64; ++d) o[d] *= corr;
                m = s;
            }
            float p = __expf(s - m);
            l += p;
            const float4* vr = (const float4*)&smV[j][0];
            #pragma unroll
            for (int d4 = 0; d4 < 16; ++d4) {
                float4 vv = vr[d4];
                o[4*d4+0] += p*vv.x; o[4*d4+1] += p*vv.y;
                o[4*d4+2] += p*vv.z; o[4*d4+3] += p*vv.w;
            }
        }
    }
    const float rl = 1.f / l;
    const size_t ob = (size_t)(b * 1024 + i0 + tid) * 768 + h * 64;
    #pragma unroll
    for (int d = 0; d < 64; ++d) psi[ob + d] = f2bf(o[d] * rl);
}

// ---------------- rel-doc flash attention (+ rv residual), bf16 psi_r [b,R,h*64]
__global__ __launch_bounds__(64) void attn_rel(
    const float* __restrict__ rkb, const float* __restrict__ kb, const float* __restrict__ vb,
    const float* __restrict__ rvb, const int* __restrict__ mask, ushort* __restrict__ psi)
{
    __shared__ float smK[64][LPAD];
    __shared__ float smV[64][LPAD];
    __shared__ float madd[64];
    const int tid = threadIdx.x;
    const int bh = blockIdx.x, b = bh / 12, h = bh % 12;
    const int i0 = blockIdx.y * 64;
    const int i = i0 + tid;                 // query (relation) row, valid if < 97
    const size_t kbase = (size_t)b * 1024 * 768 + h * 64;
    const size_t rbase = (size_t)b * 97 * 768 + h * 64;

    for (int r = 0; r < 64; ++r)
        smK[r][tid] = (i0 + r < 97) ? rkb[rbase + (size_t)(i0 + r) * 768 + tid] : 0.f;
    __syncthreads();
    float q[64];
    {
        const float4* qr = (const float4*)&smK[tid][0];
        #pragma unroll
        for (int d4 = 0; d4 < 16; ++d4) {
            float4 v = qr[d4];
            q[4*d4+0] = v.x; q[4*d4+1] = v.y; q[4*d4+2] = v.z; q[4*d4+3] = v.w;
        }
    }
    float m = -3.0e38f, l = 0.f;
    float o[64];
    #pragma unroll
    for (int d = 0; d < 64; ++d) o[d] = 0.f;

    for (int jt = 0; jt < 16; ++jt) {
        __syncthreads();
        const int j0 = jt * 64;
        for (int r = 0; r < 64; ++r) {
            smK[r][tid] = kb[kbase + (size_t)(j0 + r) * 768 + tid];
            smV[r][tid] = vb[kbase + (size_t)(j0 + r) * 768 + tid];
        }
        madd[tid] = (mask[b * 1024 + j0 + tid] == 0) ? -1e30f : 0.f;
        __syncthreads();
        for (int j = 0; j < 64; ++j) {
            const float4* kr = (const float4*)&smK[j][0];
            float s = 0.f;
            #pragma unroll
            for (int d4 = 0; d4 < 16; ++d4) {
                float4 kv = kr[d4];
                s += q[4*d4+0]*kv.x + q[4*d4+1]*kv.y + q[4*d4+2]*kv.z + q[4*d4+3]*kv.w;
            }
            s = s * 0.125f + madd[j];
            if (s > m) {
                float corr = __expf(m - s);
                l *= corr;
                #pragma unroll
                for (int d = 0; d < 64; ++d) o[d] *= corr;
                m = s;
            }
            float p = __expf(s - m);
            l += p;
            const float4* vr = (const float4*)&smV[j][0];
            #pragma unroll
            for (int d4 = 0; d4 < 16; ++d4) {
                float4 vv = vr[d4];
                o[4*d4+0] += p*vv.x; o[4*d4+1] += p*vv.y;
                o[4*d4+2] += p*vv.z; o[4*d4+3] += p*vv.w;
            }
        }
    }
    if (i < 97) {
        const float rl = 1.f / l;
        const size_t ob = rbase + (size_t)i * 768;
        #pragma unroll
        for (int d = 0; d < 64; ++d)
            psi[ob + d] = f2bf(o[d] * rl + rvb[ob + d]);
    }
}

// ---------------- LayerNorm( gin + residual ) * g + b  -> f32 out
__global__ __launch_bounds__(256) void ln_ker(
    const float* __restrict__ gin, const float* __restrict__ resid,
    const float* __restrict__ g, const float* __restrict__ bta,
    float* __restrict__ out)
{
    const int row = blockIdx.x, tid = threadIdx.x;
    const size_t rb = (size_t)row * 768;
    float x[3], s = 0.f, s2 = 0.f;
    #pragma unroll
    for (int k2 = 0; k2 < 3; ++k2) {
        int c = k2 * 256 + tid;
        float v = gin[rb + c] + resid[rb + c];
        x[k2] = v; s += v; s2 += v * v;
    }
    #pragma unroll
    for (int off = 32; off > 0; off >>= 1) {
        s  += __shfl_down(s, off);
        s2 += __shfl_down(s2, off);
    }
    __shared__ float red[10];
    const int wv = tid >> 6;
    if ((tid & 63) == 0) { red[wv] = s; red[4 + wv] = s2; }
    __syncthreads();
    if (tid == 0) {
        float ts = red[0] + red[1] + red[2] + red[3];
        float t2 = red[4] + red[5] + red[6] + red[7];
        float mean = ts * (1.f / 768.f);
        float var = t2 * (1.f / 768.f) - mean * mean;
        red[8] = mean;
        red[9] = rsqrtf(fmaxf(var, 0.f) + 1e-6f);
    }
    __syncthreads();
    const float mean = red[8], rstd = red[9];
    #pragma unroll
    for (int k2 = 0; k2 < 3; ++k2) {
        int c = k2 * 256 + tid;
        out[rb + c] = (x[k2] - mean) * rstd * g[c] + bta[c];
    }
}

extern "C" void kernel_launch(void* const* d_in, const int* in_sizes, int n_in,
                              void* d_out, int out_size, void* d_ws, size_t ws_size,
                              hipStream_t stream) {
    const float* doc  = (const float*)d_in[0];
    const float* rel  = (const float*)d_in[1];
    const int*   mask = (const int*)d_in[2];
    const float* w_in[7] = {
        (const float*)d_in[3], (const float*)d_in[4], (const float*)d_in[5],
        (const float*)d_in[6], (const float*)d_in[7], (const float*)d_in[8],
        (const float*)d_in[9] };
    const float* ln_dg = (const float*)d_in[10];
    const float* ln_db = (const float*)d_in[11];
    const float* ln_rg = (const float*)d_in[12];
    const float* ln_rb = (const float*)d_in[13];

    char* ws = (char*)d_ws;
    size_t off = 0;
    ushort* wt[7];
    for (int i = 0; i < 7; ++i) { wt[i] = (ushort*)(ws + off); off += (size_t)768 * 768 * 2; }
    ushort* doc_bf = (ushort*)(ws + off); off += (size_t)4096 * 768 * 2;
    ushort* rel_bf = (ushort*)(ws + off); off += (size_t)388 * 768 * 2;
    float* qb   = (float*)(ws + off); off += (size_t)4096 * 768 * 4;
    float* kb   = (float*)(ws + off); off += (size_t)4096 * 768 * 4;
    float* vb   = (float*)(ws + off); off += (size_t)4096 * 768 * 4;
    float* rkb  = (float*)(ws + off); off += (size_t)388 * 768 * 4;
    float* rvb  = (float*)(ws + off); off += (size_t)388 * 768 * 4;
    float* rks  = (float*)(ws + off); off += (size_t)4 * 768 * 4;
    float* rvs  = (float*)(ws + off); off += (size_t)4 * 768 * 4;
    ushort* psi_i = (ushort*)(ws + off); off += (size_t)4096 * 768 * 2;
    ushort* psi_r = (ushort*)(ws + off); off += (size_t)388 * 768 * 2;
    // gdoc/grel alias qb/kb — both are dead after the attention kernels
    float* gdoc = qb;
    float* grel = kb;

    float* out_doc = (float*)d_out;
    float* out_rel = out_doc + (size_t)4096 * 768;

    // input converts + weight transposes
    cvt_bf16<<<dim3((4096 * 768 + 255) / 256), 256, 0, stream>>>(doc, doc_bf, 4096 * 768);
    cvt_bf16<<<dim3((388 * 768 + 255) / 256), 256, 0, stream>>>(rel, rel_bf, 388 * 768);
    for (int i = 0; i < 7; ++i)
        transpose768<<<dim3(24, 24), dim3(32, 8), 0, stream>>>(w_in[i], wt[i]);

    // projections
    gemm_bt<<<dim3(32, 6), 256, 0, stream>>>(doc_bf, wt[0], qb, 4096, 768, 768);
    gemm_bt<<<dim3(32, 6), 256, 0, stream>>>(doc_bf, wt[1], kb, 4096, 768, 768);
    gemm_bt<<<dim3(32, 6), 256, 0, stream>>>(doc_bf, wt[2], vb, 4096, 768, 768);
    gemm_bt<<<dim3(4, 6),  256, 0, stream>>>(rel_bf, wt[3], rkb, 388, 768, 768);
    gemm_bt<<<dim3(4, 6),  256, 0, stream>>>(rel_bf, wt[4], rvb, 388, 768, 768);

    // relation sums for fused_k / fused_v
    relsum<<<dim3(4, 3), 256, 0, stream>>>(rkb, rvb, rks, rvs);

    // attention
    attn_doc<<<dim3(48, 16), 64, 0, stream>>>(qb, kb, vb, rks, rvs, mask, psi_i);
    attn_rel<<<dim3(48, 2),  64, 0, stream>>>(rkb, kb, vb, rvb, mask, psi_r);

    // output projections (write into aliased qb/kb)
    gemm_bt<<<dim3(32, 6), 256, 0, stream>>>(psi_i, wt[5], gdoc, 4096, 768, 768);
    gemm_bt<<<dim3(4, 6),  256, 0, stream>>>(psi_r, wt[6], grel, 388, 768, 768);

    // layernorm + residual -> f32 outputs
    ln_ker<<<4096, 256, 0, stream>>>(gdoc, doc, ln_dg, ln_db, out_doc);
    ln_ker<<<388,  256, 0, stream>>>(grel, rel, ln_rg, ln_rb, out_rel);
}

// Round 5
// 846.304 us; speedup vs baseline: 2.2964x; 2.2964x over previous
//
#include <hip/hip_runtime.h>

typedef __attribute__((ext_vector_type(8))) short bt8;   // 8 bf16 (4 VGPR)
typedef __attribute__((ext_vector_type(4))) float f32x4; // 4 f32

__device__ __forceinline__ float bf2f(ushort u) {
    union { unsigned int i; float f; } v; v.i = ((unsigned int)u) << 16; return v.f;
}
__device__ __forceinline__ ushort f2bf(float f) {
    union { float f; unsigned int i; } v; v.f = f;
    unsigned int r = v.i + 0x7fffu + ((v.i >> 16) & 1u);
    return (ushort)(r >> 16);
}

// ---------------- f32 -> bf16 elementwise convert
__global__ __launch_bounds__(256) void cvt_bf16(const float* __restrict__ in,
                                                ushort* __restrict__ out, int n) {
    int i = blockIdx.x * 256 + threadIdx.x;
    if (i < n) out[i] = f2bf(in[i]);
}

// ---------------- weight transpose+convert: W[768,768] f32 (in,out) -> WT[768,768] bf16 (out,in)
__global__ void transpose768(const float* __restrict__ W, ushort* __restrict__ WT) {
    __shared__ float t[32][33];
    int bx = blockIdx.x * 32, by = blockIdx.y * 32;
    int x = threadIdx.x, y0 = threadIdx.y;
    for (int y = y0; y < 32; y += 8)
        t[y][x] = W[(size_t)(by + y) * 768 + bx + x];
    __syncthreads();
    for (int y = y0; y < 32; y += 8)
        WT[(size_t)(bx + y) * 768 + by + x] = f2bf(t[x][y]);
}

// ---------------- MFMA bf16 GEMM: C[M,N] f32 = A[M,K] bf16 @ BT[N,K]^T bf16
#define BM 128
#define BN 128
#define BKK 32
#define LDT 40  // halfword stride (32 + 8 pad)

__global__ __launch_bounds__(256) void gemm_bt(
    const ushort* __restrict__ A, const ushort* __restrict__ BT,
    float* __restrict__ C, int M, int N, int K)
{
    __shared__ ushort As[BM][LDT];
    __shared__ ushort Bs[BN][LDT];
    const int tid = threadIdx.x;
    const int row0 = blockIdx.x * BM, col0 = blockIdx.y * BN;
    const int wave = tid >> 6, lane = tid & 63;
    const int wm = (wave >> 1) * 64, wn = (wave & 1) * 64;
    const int lr = lane & 15, lk = (lane >> 4) * 8;
    const int sr = tid >> 2;          // staging row 0..63
    const int sc = (tid & 3) * 8;     // staging col (halfwords)

    f32x4 acc[4][4];
    for (int mi = 0; mi < 4; ++mi)
        for (int ni = 0; ni < 4; ++ni)
            acc[mi][ni] = (f32x4){0.f, 0.f, 0.f, 0.f};

    for (int kt = 0; kt < K; kt += BKK) {
        __syncthreads();
        for (int rr = sr; rr < BM; rr += 64) {
            int gr = row0 + rr;
            int4 av; av.x = av.y = av.z = av.w = 0;
            if (gr < M) av = *(const int4*)(A + (size_t)gr * K + kt + sc);
            *(int4*)&As[rr][sc] = av;
            int gc = col0 + rr;
            int4 bv; bv.x = bv.y = bv.z = bv.w = 0;
            if (gc < N) bv = *(const int4*)(BT + (size_t)gc * K + kt + sc);
            *(int4*)&Bs[rr][sc] = bv;
        }
        __syncthreads();
        bt8 af[4], bf[4];
        for (int mi = 0; mi < 4; ++mi)
            af[mi] = *(const bt8*)&As[wm + mi * 16 + lr][lk];
        for (int ni = 0; ni < 4; ++ni)
            bf[ni] = *(const bt8*)&Bs[wn + ni * 16 + lr][lk];
        for (int mi = 0; mi < 4; ++mi)
            for (int ni = 0; ni < 4; ++ni)
                acc[mi][ni] = __builtin_amdgcn_mfma_f32_16x16x32_bf16(
                    af[mi], bf[ni], acc[mi][ni], 0, 0, 0);
    }

    for (int mi = 0; mi < 4; ++mi) {
        int orow0 = row0 + wm + mi * 16 + (lane >> 4) * 4;
        for (int ni = 0; ni < 4; ++ni) {
            int ocol = col0 + wn + ni * 16 + lr;
            if (ocol >= N) continue;
            for (int r2 = 0; r2 < 4; ++r2) {
                int orow = orow0 + r2;
                if (orow < M) C[(size_t)orow * N + ocol] = acc[mi][ni][r2];
            }
        }
    }
}

// ---------------- per-(b) column sums of rk, rv over R=97 rows
__global__ void relsum(const float* __restrict__ rk, const float* __restrict__ rv,
                       float* __restrict__ rks, float* __restrict__ rvs) {
    int b = blockIdx.x;
    int c = blockIdx.y * 256 + threadIdx.x;  // 0..767
    float s1 = 0.f, s2 = 0.f;
    for (int r = 0; r < 97; ++r) {
        s1 += rk[(size_t)(b * 97 + r) * 768 + c];
        s2 += rv[(size_t)(b * 97 + r) * 768 + c];
    }
    rks[b * 768 + c] = s1;
    rvs[b * 768 + c] = s2;
}

// ---------------- in-place fused_k/fused_v: kb += rks[b], vb += rvs[b]
// (runs AFTER attn_rel consumed the raw kb/vb)
__global__ __launch_bounds__(256) void fusekv(
    float* __restrict__ kb, float* __restrict__ vb,
    const float* __restrict__ rks, const float* __restrict__ rvs)
{
    int row = blockIdx.x;                       // 0..4095
    int c = blockIdx.y * 256 + threadIdx.x;     // 0..767
    int b = row >> 10;
    size_t i = (size_t)row * 768 + c;
    kb[i] += rks[b * 768 + c];
    vb[i] += rvs[b * 768 + c];
}

// ---------------- split-K flash attention partial
// Block = 1 wave of 64 threads; lane owns one query row; handles NKEYS keys.
// Writes partial m, l (f32) and unnormalized o (bf16) per (bh, split, qrow).
template<int NKEYS>
__global__ __launch_bounds__(64) void attn_part(
    const float* __restrict__ Qp, int qstride_rows, int qmax,
    const float* __restrict__ Kp, const float* __restrict__ Vp,
    const int* __restrict__ mask,
    float* __restrict__ Mo, float* __restrict__ Lo, ushort* __restrict__ Oo,
    int nspl, int qrows)
{
    __shared__ float madd[NKEYS];
    const int tid = threadIdx.x;
    const int bh = blockIdx.x, b = bh / 12, h = bh % 12;
    const int qb = blockIdx.y, spl = blockIdx.z;
    const int k0 = spl * NKEYS;
    const size_t kbase = (size_t)b * 1024 * 768 + h * 64;
    const size_t qbase = (size_t)b * qstride_rows * 768 + h * 64;
    const int qi = qb * 64 + tid;

    for (int r = tid; r < NKEYS; r += 64)
        madd[r] = (mask[b * 1024 + k0 + r] == 0) ? -1e30f : 0.f;
    __syncthreads();

    float q[64];
    if (qi < qmax) {
        const float4* qr = (const float4*)(Qp + qbase + (size_t)qi * 768);
        #pragma unroll
        for (int d4 = 0; d4 < 16; ++d4) {
            float4 v = qr[d4];
            q[4*d4+0] = v.x; q[4*d4+1] = v.y; q[4*d4+2] = v.z; q[4*d4+3] = v.w;
        }
    } else {
        #pragma unroll
        for (int d = 0; d < 64; ++d) q[d] = 0.f;
    }

    float m = -3.0e38f, l = 0.f;
    float o[64];
    #pragma unroll
    for (int d = 0; d < 64; ++d) o[d] = 0.f;

    for (int j = 0; j < NKEYS; ++j) {
        // lane-uniform broadcast loads of key row j
        const float4* kr = (const float4*)(Kp + kbase + (size_t)(k0 + j) * 768);
        float sa0 = 0.f, sa1 = 0.f, sa2 = 0.f, sa3 = 0.f;  // 4 indep chains
        #pragma unroll
        for (int d4 = 0; d4 < 4; ++d4) {
            float4 k0v = kr[d4], k1v = kr[d4+4], k2v = kr[d4+8], k3v = kr[d4+12];
            sa0 += q[4*d4+ 0]*k0v.x + q[4*d4+ 1]*k0v.y + q[4*d4+ 2]*k0v.z + q[4*d4+ 3]*k0v.w;
            sa1 += q[4*d4+16]*k1v.x + q[4*d4+17]*k1v.y + q[4*d4+18]*k1v.z + q[4*d4+19]*k1v.w;
            sa2 += q[4*d4+32]*k2v.x + q[4*d4+33]*k2v.y + q[4*d4+34]*k2v.z + q[4*d4+35]*k2v.w;
            sa3 += q[4*d4+48]*k3v.x + q[4*d4+49]*k3v.y + q[4*d4+50]*k3v.z + q[4*d4+51]*k3v.w;
        }
        float s = ((sa0 + sa1) + (sa2 + sa3)) * 0.125f + madd[j];
        if (s > m) {
            float corr = __expf(m - s);
            l *= corr;
            #pragma unroll
            for (int d = 0; d < 64; ++d) o[d] *= corr;
            m = s;
        }
        float p = __expf(s - m);
        l += p;
        const float4* vr = (const float4*)(Vp + kbase + (size_t)(k0 + j) * 768);
        #pragma unroll
        for (int d4 = 0; d4 < 16; ++d4) {
            float4 vv = vr[d4];
            o[4*d4+0] += p*vv.x; o[4*d4+1] += p*vv.y;
            o[4*d4+2] += p*vv.z; o[4*d4+3] += p*vv.w;
        }
    }

    const int prow = (bh * nspl + spl) * qrows + qi;
    Mo[prow] = m;
    Lo[prow] = l;
    uint* op = (uint*)(Oo + (size_t)prow * 64);
    #pragma unroll
    for (int d2 = 0; d2 < 32; ++d2)
        op[d2] = (uint)f2bf(o[2*d2]) | ((uint)f2bf(o[2*d2+1]) << 16);
}

// ---------------- merge split partials -> psi (bf16), optional residual add
__global__ __launch_bounds__(64) void attn_merge(
    const float* __restrict__ Mo, const float* __restrict__ Lo, const ushort* __restrict__ Oo,
    const float* __restrict__ resid, ushort* __restrict__ psi,
    int nspl, int qrows, int qmax, int out_rows)
{
    const int tid = threadIdx.x, bh = blockIdx.x, qb = blockIdx.y;
    const int b = bh / 12, h = bh % 12;
    const int qi = qb * 64 + tid;
    if (qi >= qmax) return;
    const int pb = bh * nspl;

    float M = -3.0e38f;
    for (int s = 0; s < nspl; ++s)
        M = fmaxf(M, Mo[(pb + s) * qrows + qi]);
    float L = 0.f, O[64];
    #pragma unroll
    for (int d = 0; d < 64; ++d) O[d] = 0.f;
    for (int s = 0; s < nspl; ++s) {
        int pr = (pb + s) * qrows + qi;
        float f = __expf(Mo[pr] - M);
        L += Lo[pr] * f;
        const uint* op = (const uint*)(Oo + (size_t)pr * 64);
        #pragma unroll
        for (int d2 = 0; d2 < 32; ++d2) {
            uint u = op[d2];
            O[2*d2]   += f * bf2f((ushort)(u & 0xffffu));
            O[2*d2+1] += f * bf2f((ushort)(u >> 16));
        }
    }
    const float rl = 1.f / L;
    const size_t ob = ((size_t)b * out_rows + qi) * 768 + h * 64;
    if (resid) {
        #pragma unroll
        for (int d = 0; d < 64; ++d)
            psi[ob + d] = f2bf(O[d] * rl + resid[ob + d]);
    } else {
        #pragma unroll
        for (int d = 0; d < 64; ++d)
            psi[ob + d] = f2bf(O[d] * rl);
    }
}

// ---------------- LayerNorm( gin + residual ) * g + b  -> f32 out
__global__ __launch_bounds__(256) void ln_ker(
    const float* __restrict__ gin, const float* __restrict__ resid,
    const float* __restrict__ g, const float* __restrict__ bta,
    float* __restrict__ out)
{
    const int row = blockIdx.x, tid = threadIdx.x;
    const size_t rb = (size_t)row * 768;
    float x[3], s = 0.f, s2 = 0.f;
    #pragma unroll
    for (int k2 = 0; k2 < 3; ++k2) {
        int c = k2 * 256 + tid;
        float v = gin[rb + c] + resid[rb + c];
        x[k2] = v; s += v; s2 += v * v;
    }
    #pragma unroll
    for (int off = 32; off > 0; off >>= 1) {
        s  += __shfl_down(s, off);
        s2 += __shfl_down(s2, off);
    }
    __shared__ float red[10];
    const int wv = tid >> 6;
    if ((tid & 63) == 0) { red[wv] = s; red[4 + wv] = s2; }
    __syncthreads();
    if (tid == 0) {
        float ts = red[0] + red[1] + red[2] + red[3];
        float t2 = red[4] + red[5] + red[6] + red[7];
        float mean = ts * (1.f / 768.f);
        float var = t2 * (1.f / 768.f) - mean * mean;
        red[8] = mean;
        red[9] = rsqrtf(fmaxf(var, 0.f) + 1e-6f);
    }
    __syncthreads();
    const float mean = red[8], rstd = red[9];
    #pragma unroll
    for (int k2 = 0; k2 < 3; ++k2) {
        int c = k2 * 256 + tid;
        out[rb + c] = (x[k2] - mean) * rstd * g[c] + bta[c];
    }
}

extern "C" void kernel_launch(void* const* d_in, const int* in_sizes, int n_in,
                              void* d_out, int out_size, void* d_ws, size_t ws_size,
                              hipStream_t stream) {
    const float* doc  = (const float*)d_in[0];
    const float* rel  = (const float*)d_in[1];
    const int*   mask = (const int*)d_in[2];
    const float* w_in[7] = {
        (const float*)d_in[3], (const float*)d_in[4], (const float*)d_in[5],
        (const float*)d_in[6], (const float*)d_in[7], (const float*)d_in[8],
        (const float*)d_in[9] };
    const float* ln_dg = (const float*)d_in[10];
    const float* ln_db = (const float*)d_in[11];
    const float* ln_rg = (const float*)d_in[12];
    const float* ln_rb = (const float*)d_in[13];

    char* ws = (char*)d_ws;
    size_t off = 0;
    ushort* wt[7];
    for (int i = 0; i < 7; ++i) { wt[i] = (ushort*)(ws + off); off += (size_t)768 * 768 * 2; }
    ushort* doc_bf = (ushort*)(ws + off); off += (size_t)4096 * 768 * 2;
    ushort* rel_bf = (ushort*)(ws + off); off += (size_t)388 * 768 * 2;
    float* qb   = (float*)(ws + off); off += (size_t)4096 * 768 * 4;
    float* kb   = (float*)(ws + off); off += (size_t)4096 * 768 * 4;
    float* vb   = (float*)(ws + off); off += (size_t)4096 * 768 * 4;
    float* rkb  = (float*)(ws + off); off += (size_t)388 * 768 * 4;
    float* rvb  = (float*)(ws + off); off += (size_t)388 * 768 * 4;
    float* rks  = (float*)(ws + off); off += (size_t)4 * 768 * 4;
    float* rvs  = (float*)(ws + off); off += (size_t)4 * 768 * 4;
    ushort* psi_i = (ushort*)(ws + off); off += (size_t)4096 * 768 * 2;
    ushort* psi_r = (ushort*)(ws + off); off += (size_t)388 * 768 * 2;
    // split-K partial buffers; rel (48*16*128) aliases doc (48*4*1024) sizing
    float*  Mo = (float*)(ws + off);  off += (size_t)48 * 4 * 1024 * 4;
    float*  Lo = (float*)(ws + off);  off += (size_t)48 * 4 * 1024 * 4;
    ushort* Oo = (ushort*)(ws + off); off += (size_t)48 * 4 * 1024 * 64 * 2;
    // gdoc/grel alias qb/kb — both dead after the attention phase
    float* gdoc = qb;
    float* grel = kb;

    float* out_doc = (float*)d_out;
    float* out_rel = out_doc + (size_t)4096 * 768;

    // input converts + weight transposes
    cvt_bf16<<<dim3((4096 * 768 + 255) / 256), 256, 0, stream>>>(doc, doc_bf, 4096 * 768);
    cvt_bf16<<<dim3((388 * 768 + 255) / 256), 256, 0, stream>>>(rel, rel_bf, 388 * 768);
    for (int i = 0; i < 7; ++i)
        transpose768<<<dim3(24, 24), dim3(32, 8), 0, stream>>>(w_in[i], wt[i]);

    // projections
    gemm_bt<<<dim3(32, 6), 256, 0, stream>>>(doc_bf, wt[0], qb, 4096, 768, 768);
    gemm_bt<<<dim3(32, 6), 256, 0, stream>>>(doc_bf, wt[1], kb, 4096, 768, 768);
    gemm_bt<<<dim3(32, 6), 256, 0, stream>>>(doc_bf, wt[2], vb, 4096, 768, 768);
    gemm_bt<<<dim3(4, 6),  256, 0, stream>>>(rel_bf, wt[3], rkb, 388, 768, 768);
    gemm_bt<<<dim3(4, 6),  256, 0, stream>>>(rel_bf, wt[4], rvb, 388, 768, 768);

    // relation sums
    relsum<<<dim3(4, 3), 256, 0, stream>>>(rkb, rvb, rks, rvs);

    // rel-doc attention on RAW kb/vb (split-K: 16 splits of 64 keys)
    attn_part<64><<<dim3(48, 2, 16), 64, 0, stream>>>(
        rkb, 97, 97, kb, vb, mask, Mo, Lo, Oo, 16, 128);
    attn_merge<<<dim3(48, 2), 64, 0, stream>>>(
        Mo, Lo, Oo, rvb, psi_r, 16, 128, 97, 97);

    // fold relation sums into kb/vb in place (doc attention uses fused K/V)
    fusekv<<<dim3(4096, 3), 256, 0, stream>>>(kb, vb, rks, rvs);

    // doc-doc attention (split-K: 4 splits of 256 keys)
    attn_part<256><<<dim3(48, 16, 4), 64, 0, stream>>>(
        qb, 1024, 1024, kb, vb, mask, Mo, Lo, Oo, 4, 1024);
    attn_merge<<<dim3(48, 16), 64, 0, stream>>>(
        Mo, Lo, Oo, nullptr, psi_i, 4, 1024, 1024, 1024);

    // output projections (write into aliased qb/kb)
    gemm_bt<<<dim3(32, 6), 256, 0, stream>>>(psi_i, wt[5], gdoc, 4096, 768, 768);
    gemm_bt<<<dim3(4, 6),  256, 0, stream>>>(psi_r, wt[6], grel, 388, 768, 768);

    // layernorm + residual -> f32 outputs
    ln_ker<<<4096, 256, 0, stream>>>(gdoc, doc, ln_dg, ln_db, out_doc);
    ln_ker<<<388,  256, 0, stream>>>(grel, rel, ln_rg, ln_rb, out_rel);
}

// Round 6
// 398.224 us; speedup vs baseline: 4.8803x; 2.1252x over previous
//
#include <hip/hip_runtime.h>

typedef __attribute__((ext_vector_type(8))) short bt8;   // 8 bf16 (4 VGPR)
typedef __attribute__((ext_vector_type(4))) float f32x4; // 4 f32

__device__ __forceinline__ float bf2f(ushort u) {
    union { unsigned int i; float f; } v; v.i = ((unsigned int)u) << 16; return v.f;
}
__device__ __forceinline__ ushort f2bf(float f) {
    union { float f; unsigned int i; } v; v.f = f;
    unsigned int r = v.i + 0x7fffu + ((v.i >> 16) & 1u);
    return (ushort)(r >> 16);
}

// ---------------- f32 -> bf16 elementwise convert
__global__ __launch_bounds__(256) void cvt_bf16(const float* __restrict__ in,
                                                ushort* __restrict__ out, int n) {
    int i = blockIdx.x * 256 + threadIdx.x;
    if (i < n) out[i] = f2bf(in[i]);
}

// ---------------- weight transpose+convert: W[768,768] f32 (in,out) -> WT[768,768] bf16 (out,in)
__global__ void transpose768(const float* __restrict__ W, ushort* __restrict__ WT) {
    __shared__ float t[32][33];
    int bx = blockIdx.x * 32, by = blockIdx.y * 32;
    int x = threadIdx.x, y0 = threadIdx.y;
    for (int y = y0; y < 32; y += 8)
        t[y][x] = W[(size_t)(by + y) * 768 + bx + x];
    __syncthreads();
    for (int y = y0; y < 32; y += 8)
        WT[(size_t)(bx + y) * 768 + by + x] = f2bf(t[x][y]);
}

// ---------------- MFMA bf16 GEMM: C[M,N] f32 = A[M,K] bf16 @ BT[N,K]^T bf16
#define BM 128
#define BN 128
#define BKK 32
#define LDT 40  // halfword stride (32 + 8 pad)

__global__ __launch_bounds__(256) void gemm_bt(
    const ushort* __restrict__ A, const ushort* __restrict__ BT,
    float* __restrict__ C, int M, int N, int K)
{
    __shared__ ushort As[BM][LDT];
    __shared__ ushort Bs[BN][LDT];
    const int tid = threadIdx.x;
    const int row0 = blockIdx.x * BM, col0 = blockIdx.y * BN;
    const int wave = tid >> 6, lane = tid & 63;
    const int wm = (wave >> 1) * 64, wn = (wave & 1) * 64;
    const int lr = lane & 15, lk = (lane >> 4) * 8;
    const int sr = tid >> 2;          // staging row 0..63
    const int sc = (tid & 3) * 8;     // staging col (halfwords)

    f32x4 acc[4][4];
    for (int mi = 0; mi < 4; ++mi)
        for (int ni = 0; ni < 4; ++ni)
            acc[mi][ni] = (f32x4){0.f, 0.f, 0.f, 0.f};

    for (int kt = 0; kt < K; kt += BKK) {
        __syncthreads();
        for (int rr = sr; rr < BM; rr += 64) {
            int gr = row0 + rr;
            int4 av; av.x = av.y = av.z = av.w = 0;
            if (gr < M) av = *(const int4*)(A + (size_t)gr * K + kt + sc);
            *(int4*)&As[rr][sc] = av;
            int gc = col0 + rr;
            int4 bv; bv.x = bv.y = bv.z = bv.w = 0;
            if (gc < N) bv = *(const int4*)(BT + (size_t)gc * K + kt + sc);
            *(int4*)&Bs[rr][sc] = bv;
        }
        __syncthreads();
        bt8 af[4], bf[4];
        for (int mi = 0; mi < 4; ++mi)
            af[mi] = *(const bt8*)&As[wm + mi * 16 + lr][lk];
        for (int ni = 0; ni < 4; ++ni)
            bf[ni] = *(const bt8*)&Bs[wn + ni * 16 + lr][lk];
        for (int mi = 0; mi < 4; ++mi)
            for (int ni = 0; ni < 4; ++ni)
                acc[mi][ni] = __builtin_amdgcn_mfma_f32_16x16x32_bf16(
                    af[mi], bf[ni], acc[mi][ni], 0, 0, 0);
    }

    for (int mi = 0; mi < 4; ++mi) {
        int orow0 = row0 + wm + mi * 16 + (lane >> 4) * 4;
        for (int ni = 0; ni < 4; ++ni) {
            int ocol = col0 + wn + ni * 16 + lr;
            if (ocol >= N) continue;
            for (int r2 = 0; r2 < 4; ++r2) {
                int orow = orow0 + r2;
                if (orow < M) C[(size_t)orow * N + ocol] = acc[mi][ni][r2];
            }
        }
    }
}

// ---------------- per-(b) column sums of rk, rv over R=97 rows
__global__ void relsum(const float* __restrict__ rk, const float* __restrict__ rv,
                       float* __restrict__ rks, float* __restrict__ rvs) {
    int b = blockIdx.x;
    int c = blockIdx.y * 256 + threadIdx.x;  // 0..767
    float s1 = 0.f, s2 = 0.f;
    for (int r = 0; r < 97; ++r) {
        s1 += rk[(size_t)(b * 97 + r) * 768 + c];
        s2 += rv[(size_t)(b * 97 + r) * 768 + c];
    }
    rks[b * 768 + c] = s1;
    rvs[b * 768 + c] = s2;
}

// ---------------- in-place fused_k/fused_v: kb += rks[b], vb += rvs[b]
__global__ __launch_bounds__(256) void fusekv(
    float* __restrict__ kb, float* __restrict__ vb,
    const float* __restrict__ rks, const float* __restrict__ rvs)
{
    int row = blockIdx.x;                       // 0..4095
    int c = blockIdx.y * 256 + threadIdx.x;     // 0..767
    int b = row >> 10;
    size_t i = (size_t)row * 768 + c;
    kb[i] += rks[b * 768 + c];
    vb[i] += rvs[b * 768 + c];
}

// ---------------- MFMA flash attention partial (split-K)
// Block: 256 thr = 4 waves, each wave owns 16 q-rows (block = 64 q-rows).
// Iterates ntiles key-tiles of 64; writes partial m,l,unnorm-O(bf16).
__global__ __launch_bounds__(256) void attn_mfma(
    const float* __restrict__ Qp, int qstride_rows, int qmax,
    const float* __restrict__ Kp, const float* __restrict__ Vp,
    const int* __restrict__ mask,
    float* __restrict__ Mo, float* __restrict__ Lo, ushort* __restrict__ Oo,
    int nspl, int ntiles, int qrows)
{
    __shared__ ushort Ks[64][72];       // [key][k]  (A/B frag k-contiguous)
    __shared__ ushort Vt[64][72];       // [d][key]  (transposed V)
    __shared__ ushort Ps[4][16][72];    // per-wave P tile [qrow][key]
    __shared__ float  madd[64];

    const int tid = threadIdx.x;
    const int wv = tid >> 6, lane = tid & 63;
    const int lr = lane & 15, lk = (lane >> 4) * 8, rg = lane >> 4;
    const int bh = blockIdx.x, b = bh / 12, h = bh % 12;
    const int qb = blockIdx.y, spl = blockIdx.z;
    const int q0 = qb * 64 + wv * 16;

    const size_t kvbase = (size_t)b * 1024 * 768 + h * 64;
    const size_t qbase  = (size_t)b * qstride_rows * 768 + h * 64;

    // Q fragments (row = q0+lr, k = kk*32+lk), f32 -> bf16
    bt8 qf[2];
    {
        const int qi = q0 + lr;
        #pragma unroll
        for (int kk = 0; kk < 2; ++kk) {
            float f[8];
            if (qi < qmax) {
                const float4* qp = (const float4*)(Qp + qbase + (size_t)qi * 768 + kk * 32 + lk);
                float4 a = qp[0], c = qp[1];
                f[0]=a.x; f[1]=a.y; f[2]=a.z; f[3]=a.w;
                f[4]=c.x; f[5]=c.y; f[6]=c.z; f[7]=c.w;
            } else {
                #pragma unroll
                for (int j = 0; j < 8; ++j) f[j] = 0.f;
            }
            bt8 t;
            #pragma unroll
            for (int j = 0; j < 8; ++j) t[j] = (short)f2bf(f[j]);
            qf[kk] = t;
        }
    }

    f32x4 acc[4];
    #pragma unroll
    for (int dg = 0; dg < 4; ++dg) acc[dg] = (f32x4){0.f, 0.f, 0.f, 0.f};
    float m_r[4], l_r[4];
    #pragma unroll
    for (int r = 0; r < 4; ++r) { m_r[r] = -3.0e38f; l_r[r] = 0.f; }

    for (int t = 0; t < ntiles; ++t) {
        const int k0 = (spl * ntiles + t) * 64;
        __syncthreads();
        // stage K tile [64][64] f32->bf16 (thread: row=tid>>2, 16 cols)
        {
            const int row = tid >> 2, c0 = (tid & 3) * 16;
            const float4* src = (const float4*)(Kp + kvbase + (size_t)(k0 + row) * 768 + c0);
            float4 f0 = src[0], f1 = src[1], f2 = src[2], f3 = src[3];
            float f[16] = {f0.x,f0.y,f0.z,f0.w, f1.x,f1.y,f1.z,f1.w,
                           f2.x,f2.y,f2.z,f2.w, f3.x,f3.y,f3.z,f3.w};
            uint* d32 = (uint*)&Ks[row][c0];
            #pragma unroll
            for (int i = 0; i < 8; ++i)
                d32[i] = (uint)f2bf(f[2*i]) | ((uint)f2bf(f[2*i+1]) << 16);
        }
        // stage V tile transposed: Vt[d][key]
        {
            const int key = tid >> 2, c0 = (tid & 3) * 16;
            const float4* src = (const float4*)(Vp + kvbase + (size_t)(k0 + key) * 768 + c0);
            float4 f0 = src[0], f1 = src[1], f2 = src[2], f3 = src[3];
            float f[16] = {f0.x,f0.y,f0.z,f0.w, f1.x,f1.y,f1.z,f1.w,
                           f2.x,f2.y,f2.z,f2.w, f3.x,f3.y,f3.z,f3.w};
            #pragma unroll
            for (int j = 0; j < 16; ++j)
                Vt[c0 + j][key] = f2bf(f[j]);
        }
        if (tid < 64)
            madd[tid] = (mask[b * 1024 + k0 + tid] == 0) ? -1e30f : 0.f;
        __syncthreads();

        // S = Q K^T : 8 MFMAs -> sf[kg][r], key = kg*16+lr, qrow = q0+rg*4+r
        f32x4 sf[4];
        #pragma unroll
        for (int kg = 0; kg < 4; ++kg) {
            f32x4 s4 = (f32x4){0.f, 0.f, 0.f, 0.f};
            #pragma unroll
            for (int kk = 0; kk < 2; ++kk) {
                bt8 kf = *(const bt8*)&Ks[kg * 16 + lr][kk * 32 + lk];
                s4 = __builtin_amdgcn_mfma_f32_16x16x32_bf16(qf[kk], kf, s4, 0, 0, 0);
            }
            sf[kg] = s4;
        }

        // online softmax (per reg r = qrow)
        float pv[4][4];
        #pragma unroll
        for (int r = 0; r < 4; ++r) {
            float sv0 = sf[0][r] * 0.125f + madd[lr];
            float sv1 = sf[1][r] * 0.125f + madd[16 + lr];
            float sv2 = sf[2][r] * 0.125f + madd[32 + lr];
            float sv3 = sf[3][r] * 0.125f + madd[48 + lr];
            float mx = fmaxf(fmaxf(sv0, sv1), fmaxf(sv2, sv3));
            mx = fmaxf(mx, __shfl_xor(mx, 1));
            mx = fmaxf(mx, __shfl_xor(mx, 2));
            mx = fmaxf(mx, __shfl_xor(mx, 4));
            mx = fmaxf(mx, __shfl_xor(mx, 8));
            float mn = fmaxf(m_r[r], mx);
            float corr = __expf(m_r[r] - mn);
            m_r[r] = mn;
            float p0 = __expf(sv0 - mn), p1 = __expf(sv1 - mn);
            float p2 = __expf(sv2 - mn), p3 = __expf(sv3 - mn);
            pv[0][r] = p0; pv[1][r] = p1; pv[2][r] = p2; pv[3][r] = p3;
            float ps = (p0 + p1) + (p2 + p3);
            ps += __shfl_xor(ps, 1);
            ps += __shfl_xor(ps, 2);
            ps += __shfl_xor(ps, 4);
            ps += __shfl_xor(ps, 8);
            l_r[r] = l_r[r] * corr + ps;
            #pragma unroll
            for (int dg = 0; dg < 4; ++dg) acc[dg][r] *= corr;
        }

        // P -> LDS (D-layout scatter), then read back as A-frag
        #pragma unroll
        for (int kg = 0; kg < 4; ++kg)
            #pragma unroll
            for (int r = 0; r < 4; ++r)
                Ps[wv][rg * 4 + r][kg * 16 + lr] = f2bf(pv[kg][r]);

        // PV: O += P * V  (A=P row=qrow, B=Vt col=d, k=key)
        #pragma unroll
        for (int kk = 0; kk < 2; ++kk) {
            bt8 pa = *(const bt8*)&Ps[wv][lr][kk * 32 + lk];
            #pragma unroll
            for (int dg = 0; dg < 4; ++dg) {
                bt8 vf = *(const bt8*)&Vt[dg * 16 + lr][kk * 32 + lk];
                acc[dg] = __builtin_amdgcn_mfma_f32_16x16x32_bf16(pa, vf, acc[dg], 0, 0, 0);
            }
        }
    }

    // write partials
    if (lr == 0) {
        #pragma unroll
        for (int r = 0; r < 4; ++r) {
            int qi = q0 + rg * 4 + r;
            int prow = (bh * nspl + spl) * qrows + qi;
            Mo[prow] = m_r[r];
            Lo[prow] = l_r[r];
        }
    }
    #pragma unroll
    for (int r = 0; r < 4; ++r) {
        int qi = q0 + rg * 4 + r;
        size_t orow = ((size_t)(bh * nspl + spl) * qrows + qi) * 64;
        #pragma unroll
        for (int dg = 0; dg < 4; ++dg)
            Oo[orow + dg * 16 + lr] = f2bf(acc[dg][r]);
    }
}

// ---------------- merge split partials -> psi (bf16), optional residual add
__global__ __launch_bounds__(64) void attn_merge(
    const float* __restrict__ Mo, const float* __restrict__ Lo, const ushort* __restrict__ Oo,
    const float* __restrict__ resid, ushort* __restrict__ psi,
    int nspl, int qrows, int qmax, int out_rows)
{
    const int tid = threadIdx.x, bh = blockIdx.x, qb = blockIdx.y;
    const int b = bh / 12, h = bh % 12;
    const int qi = qb * 64 + tid;
    if (qi >= qmax) return;
    const int pb = bh * nspl;

    float M = -3.0e38f;
    for (int s = 0; s < nspl; ++s)
        M = fmaxf(M, Mo[(pb + s) * qrows + qi]);
    float L = 0.f, O[64];
    #pragma unroll
    for (int d = 0; d < 64; ++d) O[d] = 0.f;
    for (int s = 0; s < nspl; ++s) {
        int pr = (pb + s) * qrows + qi;
        float f = __expf(Mo[pr] - M);
        L += Lo[pr] * f;
        const uint* op = (const uint*)(Oo + (size_t)pr * 64);
        #pragma unroll
        for (int d2 = 0; d2 < 32; ++d2) {
            uint u = op[d2];
            O[2*d2]   += f * bf2f((ushort)(u & 0xffffu));
            O[2*d2+1] += f * bf2f((ushort)(u >> 16));
        }
    }
    const float rl = 1.f / L;
    const size_t ob = ((size_t)b * out_rows + qi) * 768 + h * 64;
    if (resid) {
        #pragma unroll
        for (int d = 0; d < 64; ++d)
            psi[ob + d] = f2bf(O[d] * rl + resid[ob + d]);
    } else {
        #pragma unroll
        for (int d = 0; d < 64; ++d)
            psi[ob + d] = f2bf(O[d] * rl);
    }
}

// ---------------- LayerNorm( gin + residual ) * g + b  -> f32 out
__global__ __launch_bounds__(256) void ln_ker(
    const float* __restrict__ gin, const float* __restrict__ resid,
    const float* __restrict__ g, const float* __restrict__ bta,
    float* __restrict__ out)
{
    const int row = blockIdx.x, tid = threadIdx.x;
    const size_t rb = (size_t)row * 768;
    float x[3], s = 0.f, s2 = 0.f;
    #pragma unroll
    for (int k2 = 0; k2 < 3; ++k2) {
        int c = k2 * 256 + tid;
        float v = gin[rb + c] + resid[rb + c];
        x[k2] = v; s += v; s2 += v * v;
    }
    #pragma unroll
    for (int off = 32; off > 0; off >>= 1) {
        s  += __shfl_down(s, off);
        s2 += __shfl_down(s2, off);
    }
    __shared__ float red[10];
    const int wv = tid >> 6;
    if ((tid & 63) == 0) { red[wv] = s; red[4 + wv] = s2; }
    __syncthreads();
    if (tid == 0) {
        float ts = red[0] + red[1] + red[2] + red[3];
        float t2 = red[4] + red[5] + red[6] + red[7];
        float mean = ts * (1.f / 768.f);
        float var = t2 * (1.f / 768.f) - mean * mean;
        red[8] = mean;
        red[9] = rsqrtf(fmaxf(var, 0.f) + 1e-6f);
    }
    __syncthreads();
    const float mean = red[8], rstd = red[9];
    #pragma unroll
    for (int k2 = 0; k2 < 3; ++k2) {
        int c = k2 * 256 + tid;
        out[rb + c] = (x[k2] - mean) * rstd * g[c] + bta[c];
    }
}

extern "C" void kernel_launch(void* const* d_in, const int* in_sizes, int n_in,
                              void* d_out, int out_size, void* d_ws, size_t ws_size,
                              hipStream_t stream) {
    const float* doc  = (const float*)d_in[0];
    const float* rel  = (const float*)d_in[1];
    const int*   mask = (const int*)d_in[2];
    const float* w_in[7] = {
        (const float*)d_in[3], (const float*)d_in[4], (const float*)d_in[5],
        (const float*)d_in[6], (const float*)d_in[7], (const float*)d_in[8],
        (const float*)d_in[9] };
    const float* ln_dg = (const float*)d_in[10];
    const float* ln_db = (const float*)d_in[11];
    const float* ln_rg = (const float*)d_in[12];
    const float* ln_rb = (const float*)d_in[13];

    char* ws = (char*)d_ws;
    size_t off = 0;
    ushort* wt[7];
    for (int i = 0; i < 7; ++i) { wt[i] = (ushort*)(ws + off); off += (size_t)768 * 768 * 2; }
    ushort* doc_bf = (ushort*)(ws + off); off += (size_t)4096 * 768 * 2;
    ushort* rel_bf = (ushort*)(ws + off); off += (size_t)388 * 768 * 2;
    float* qb   = (float*)(ws + off); off += (size_t)4096 * 768 * 4;
    float* kb   = (float*)(ws + off); off += (size_t)4096 * 768 * 4;
    float* vb   = (float*)(ws + off); off += (size_t)4096 * 768 * 4;
    float* rkb  = (float*)(ws + off); off += (size_t)388 * 768 * 4;
    float* rvb  = (float*)(ws + off); off += (size_t)388 * 768 * 4;
    float* rks  = (float*)(ws + off); off += (size_t)4 * 768 * 4;
    float* rvs  = (float*)(ws + off); off += (size_t)4 * 768 * 4;
    ushort* psi_i = (ushort*)(ws + off); off += (size_t)4096 * 768 * 2;
    ushort* psi_r = (ushort*)(ws + off); off += (size_t)388 * 768 * 2;
    // split partials (doc: 48*2*1024 rows; rel: 48*8*128 rows — alias)
    float*  Mo = (float*)(ws + off);  off += (size_t)48 * 2 * 1024 * 4;
    float*  Lo = (float*)(ws + off);  off += (size_t)48 * 2 * 1024 * 4;
    ushort* Oo = (ushort*)(ws + off); off += (size_t)48 * 2 * 1024 * 64 * 2;
    float* gdoc = qb;   // aliases, dead after attention
    float* grel = kb;

    float* out_doc = (float*)d_out;
    float* out_rel = out_doc + (size_t)4096 * 768;

    // input converts + weight transposes
    cvt_bf16<<<dim3((4096 * 768 + 255) / 256), 256, 0, stream>>>(doc, doc_bf, 4096 * 768);
    cvt_bf16<<<dim3((388 * 768 + 255) / 256), 256, 0, stream>>>(rel, rel_bf, 388 * 768);
    for (int i = 0; i < 7; ++i)
        transpose768<<<dim3(24, 24), dim3(32, 8), 0, stream>>>(w_in[i], wt[i]);

    // projections
    gemm_bt<<<dim3(32, 6), 256, 0, stream>>>(doc_bf, wt[0], qb, 4096, 768, 768);
    gemm_bt<<<dim3(32, 6), 256, 0, stream>>>(doc_bf, wt[1], kb, 4096, 768, 768);
    gemm_bt<<<dim3(32, 6), 256, 0, stream>>>(doc_bf, wt[2], vb, 4096, 768, 768);
    gemm_bt<<<dim3(4, 6),  256, 0, stream>>>(rel_bf, wt[3], rkb, 388, 768, 768);
    gemm_bt<<<dim3(4, 6),  256, 0, stream>>>(rel_bf, wt[4], rvb, 388, 768, 768);

    // relation sums
    relsum<<<dim3(4, 3), 256, 0, stream>>>(rkb, rvb, rks, rvs);

    // rel-doc attention on RAW kb/vb: 8 splits x 2 tiles of 64 keys
    attn_mfma<<<dim3(48, 2, 8), 256, 0, stream>>>(
        rkb, 97, 97, kb, vb, mask, Mo, Lo, Oo, 8, 2, 128);
    attn_merge<<<dim3(48, 2), 64, 0, stream>>>(
        Mo, Lo, Oo, rvb, psi_r, 8, 128, 97, 97);

    // fold relation sums into kb/vb in place
    fusekv<<<dim3(4096, 3), 256, 0, stream>>>(kb, vb, rks, rvs);

    // doc-doc attention: 2 splits x 8 tiles of 64 keys
    attn_mfma<<<dim3(48, 16, 2), 256, 0, stream>>>(
        qb, 1024, 1024, kb, vb, mask, Mo, Lo, Oo, 2, 8, 1024);
    attn_merge<<<dim3(48, 16), 64, 0, stream>>>(
        Mo, Lo, Oo, nullptr, psi_i, 2, 1024, 1024, 1024);

    // output projections (write into aliased qb/kb)
    gemm_bt<<<dim3(32, 6), 256, 0, stream>>>(psi_i, wt[5], gdoc, 4096, 768, 768);
    gemm_bt<<<dim3(4, 6),  256, 0, stream>>>(psi_r, wt[6], grel, 388, 768, 768);

    // layernorm + residual -> f32 outputs
    ln_ker<<<4096, 256, 0, stream>>>(gdoc, doc, ln_dg, ln_db, out_doc);
    ln_ker<<<388,  256, 0, stream>>>(grel, rel, ln_rg, ln_rb, out_rel);
}

// Round 7
// 265.353 us; speedup vs baseline: 7.3241x; 1.5007x over previous
//
#include <hip/hip_runtime.h>

typedef __attribute__((ext_vector_type(8))) short bt8;   // 8 bf16 (4 VGPR)
typedef __attribute__((ext_vector_type(4))) float f32x4; // 4 f32

__device__ __forceinline__ float bf2f(ushort u) {
    union { unsigned int i; float f; } v; v.i = ((unsigned int)u) << 16; return v.f;
}
__device__ __forceinline__ ushort f2bf(float f) {
    union { float f; unsigned int i; } v; v.f = f;
    unsigned int r = v.i + 0x7fffu + ((v.i >> 16) & 1u);
    return (ushort)(r >> 16);
}

// ---------------- f32 -> bf16 elementwise convert
__global__ __launch_bounds__(256) void cvt_bf16(const float* __restrict__ in,
                                                ushort* __restrict__ out, int n) {
    int i = blockIdx.x * 256 + threadIdx.x;
    if (i < n) out[i] = f2bf(in[i]);
}

// ---------------- weight transpose+convert: W[768,768] f32 (in,out) -> WT[768,768] bf16 (out,in)
__global__ void transpose768(const float* __restrict__ W, ushort* __restrict__ WT) {
    __shared__ float t[32][33];
    int bx = blockIdx.x * 32, by = blockIdx.y * 32;
    int x = threadIdx.x, y0 = threadIdx.y;
    for (int y = y0; y < 32; y += 8)
        t[y][x] = W[(size_t)(by + y) * 768 + bx + x];
    __syncthreads();
    for (int y = y0; y < 32; y += 8)
        WT[(size_t)(bx + y) * 768 + by + x] = f2bf(t[x][y]);
}

// ---------------- templated MFMA bf16 GEMM: C[M,N] = A[M,K] @ BT[N,K]^T
// 4 waves in a (4/WN) x WN grid; each wave MI x NI frags of 16x16.
#define BKK 32
#define LDT 40  // halfword stride (32 + 8 pad)

template<int TBM, int TBN, int WN, int MI, int NI, bool BF16O>
__global__ __launch_bounds__(256) void gemm_t(
    const ushort* __restrict__ A, const ushort* __restrict__ BT,
    void* __restrict__ Cv, int M, int N, int K)
{
    __shared__ ushort As[TBM][LDT];
    __shared__ ushort Bs[TBN][LDT];
    const int tid = threadIdx.x;
    const int row0 = blockIdx.x * TBM, col0 = blockIdx.y * TBN;
    const int wave = tid >> 6, lane = tid & 63;
    const int wm = (wave / WN) * (MI * 16), wn = (wave % WN) * (NI * 16);
    const int lr = lane & 15, lk = (lane >> 4) * 8;
    const int sr = tid >> 2;          // staging row 0..63
    const int sc = (tid & 3) * 8;     // staging col (halfwords)

    f32x4 acc[MI][NI];
    #pragma unroll
    for (int mi = 0; mi < MI; ++mi)
        #pragma unroll
        for (int ni = 0; ni < NI; ++ni)
            acc[mi][ni] = (f32x4){0.f, 0.f, 0.f, 0.f};

    for (int kt = 0; kt < K; kt += BKK) {
        __syncthreads();
        #pragma unroll
        for (int rr = 0; rr < TBM; rr += 64) {
            int gr = row0 + rr + sr;
            int4 av; av.x = av.y = av.z = av.w = 0;
            if (gr < M) av = *(const int4*)(A + (size_t)gr * K + kt + sc);
            *(int4*)&As[rr + sr][sc] = av;
        }
        #pragma unroll
        for (int rr = 0; rr < TBN; rr += 64) {
            int gc = col0 + rr + sr;
            int4 bv; bv.x = bv.y = bv.z = bv.w = 0;
            if (gc < N) bv = *(const int4*)(BT + (size_t)gc * K + kt + sc);
            *(int4*)&Bs[rr + sr][sc] = bv;
        }
        __syncthreads();
        bt8 af[MI], bf[NI];
        #pragma unroll
        for (int mi = 0; mi < MI; ++mi)
            af[mi] = *(const bt8*)&As[wm + mi * 16 + lr][lk];
        #pragma unroll
        for (int ni = 0; ni < NI; ++ni)
            bf[ni] = *(const bt8*)&Bs[wn + ni * 16 + lr][lk];
        #pragma unroll
        for (int mi = 0; mi < MI; ++mi)
            #pragma unroll
            for (int ni = 0; ni < NI; ++ni)
                acc[mi][ni] = __builtin_amdgcn_mfma_f32_16x16x32_bf16(
                    af[mi], bf[ni], acc[mi][ni], 0, 0, 0);
    }

    #pragma unroll
    for (int mi = 0; mi < MI; ++mi) {
        int orow0 = row0 + wm + mi * 16 + (lane >> 4) * 4;
        #pragma unroll
        for (int ni = 0; ni < NI; ++ni) {
            int ocol = col0 + wn + ni * 16 + lr;
            if (ocol >= N) continue;
            #pragma unroll
            for (int r2 = 0; r2 < 4; ++r2) {
                int orow = orow0 + r2;
                if (orow < M) {
                    if (BF16O)
                        ((ushort*)Cv)[(size_t)orow * N + ocol] = f2bf(acc[mi][ni][r2]);
                    else
                        ((float*)Cv)[(size_t)orow * N + ocol] = acc[mi][ni][r2];
                }
            }
        }
    }
}

// ---------------- per-(b) column sums of rel K/V from fused rkv (f32, stride 1536)
__global__ void relsum(const float* __restrict__ rkv,
                       float* __restrict__ rks, float* __restrict__ rvs) {
    int b = blockIdx.x;
    int c = blockIdx.y * 256 + threadIdx.x;  // 0..767
    float s1 = 0.f, s2 = 0.f;
    for (int r = 0; r < 97; ++r) {
        const float* row = rkv + (size_t)(b * 97 + r) * 1536;
        s1 += row[c];
        s2 += row[768 + c];
    }
    rks[b * 768 + c] = s1;
    rvs[b * 768 + c] = s2;
}

// ---------------- fused_k/fused_v (bf16): kf = k + rks[b], vf = v + rvs[b]
__global__ __launch_bounds__(256) void fusekv(
    const ushort* __restrict__ qkv, const float* __restrict__ rks,
    const float* __restrict__ rvs, ushort* __restrict__ kf, ushort* __restrict__ vf)
{
    int row = blockIdx.x;                       // 0..4095
    int c = blockIdx.y * 256 + threadIdx.x;     // 0..767
    int b = row >> 10;
    size_t qi = (size_t)row * 2304;
    size_t oi = (size_t)row * 768 + c;
    kf[oi] = f2bf(bf2f(qkv[qi + 768 + c]) + rks[b * 768 + c]);
    vf[oi] = f2bf(bf2f(qkv[qi + 1536 + c]) + rvs[b * 768 + c]);
}

// ---------------- MFMA flash attention partial (split-K), bf16 inputs
// Block: 256 thr = 4 waves, each wave owns 16 q-rows (block = 64 q-rows).
__global__ __launch_bounds__(256) void attn_mfma(
    const ushort* __restrict__ Qp, int qstride, size_t qbstride, int qmax,
    const ushort* __restrict__ Kp, const ushort* __restrict__ Vp,
    int kvstride, size_t kvbstride,
    const int* __restrict__ mask,
    float* __restrict__ Mo, float* __restrict__ Lo, ushort* __restrict__ Oo,
    int nspl, int ntiles, int qrows)
{
    __shared__ ushort Ks[64][72];       // [key][k]
    __shared__ ushort Vt[64][72];       // [d][key]
    __shared__ ushort Ps[4][16][72];    // per-wave P tile [qrow][key]
    __shared__ float  madd[64];

    const int tid = threadIdx.x;
    const int wv = tid >> 6, lane = tid & 63;
    const int lr = lane & 15, lk = (lane >> 4) * 8, rg = lane >> 4;
    const int bh = blockIdx.x, b = bh / 12, h = bh % 12;
    const int qb = blockIdx.y, spl = blockIdx.z;
    const int q0 = qb * 64 + wv * 16;

    const size_t kvbase = (size_t)b * kvbstride + h * 64;
    const size_t qbase  = (size_t)b * qbstride + h * 64;

    // Q fragments (bf16 direct)
    bt8 qf[2];
    {
        const int qi = q0 + lr;
        if (qi < qmax) {
            const ushort* qp = Qp + qbase + (size_t)qi * qstride + lk;
            qf[0] = *(const bt8*)qp;
            qf[1] = *(const bt8*)(qp + 32);
        } else {
            #pragma unroll
            for (int j = 0; j < 8; ++j) { qf[0][j] = 0; qf[1][j] = 0; }
        }
    }

    f32x4 acc[4];
    #pragma unroll
    for (int dg = 0; dg < 4; ++dg) acc[dg] = (f32x4){0.f, 0.f, 0.f, 0.f};
    float m_r[4], l_r[4];
    #pragma unroll
    for (int r = 0; r < 4; ++r) { m_r[r] = -3.0e38f; l_r[r] = 0.f; }

    const int key = tid >> 2, c0 = (tid & 3) * 16;

    for (int t = 0; t < ntiles; ++t) {
        const int k0 = (spl * ntiles + t) * 64;
        __syncthreads();
        // stage K tile (pure bf16 copy: 32B per thread)
        {
            const ushort* src = Kp + kvbase + (size_t)(k0 + key) * kvstride + c0;
            *(int4*)&Ks[key][c0]     = *(const int4*)src;
            *(int4*)&Ks[key][c0 + 8] = *(const int4*)(src + 8);
        }
        // stage V transposed (16 b16 scatters per thread)
        {
            const ushort* src = Vp + kvbase + (size_t)(k0 + key) * kvstride + c0;
            ushort tmp[16];
            *(int4*)tmp       = *(const int4*)src;
            *(int4*)(tmp + 8) = *(const int4*)(src + 8);
            #pragma unroll
            for (int j = 0; j < 16; ++j)
                Vt[c0 + j][key] = tmp[j];
        }
        if (tid < 64)
            madd[tid] = (mask[b * 1024 + k0 + tid] == 0) ? -1e30f : 0.f;
        __syncthreads();

        // S = Q K^T
        f32x4 sf[4];
        #pragma unroll
        for (int kg = 0; kg < 4; ++kg) {
            f32x4 s4 = (f32x4){0.f, 0.f, 0.f, 0.f};
            #pragma unroll
            for (int kk = 0; kk < 2; ++kk) {
                bt8 kf2 = *(const bt8*)&Ks[kg * 16 + lr][kk * 32 + lk];
                s4 = __builtin_amdgcn_mfma_f32_16x16x32_bf16(qf[kk], kf2, s4, 0, 0, 0);
            }
            sf[kg] = s4;
        }

        // online softmax (per reg r)
        float pv[4][4];
        #pragma unroll
        for (int r = 0; r < 4; ++r) {
            float sv0 = sf[0][r] * 0.125f + madd[lr];
            float sv1 = sf[1][r] * 0.125f + madd[16 + lr];
            float sv2 = sf[2][r] * 0.125f + madd[32 + lr];
            float sv3 = sf[3][r] * 0.125f + madd[48 + lr];
            float mx = fmaxf(fmaxf(sv0, sv1), fmaxf(sv2, sv3));
            mx = fmaxf(mx, __shfl_xor(mx, 1));
            mx = fmaxf(mx, __shfl_xor(mx, 2));
            mx = fmaxf(mx, __shfl_xor(mx, 4));
            mx = fmaxf(mx, __shfl_xor(mx, 8));
            float mn = fmaxf(m_r[r], mx);
            float corr = __expf(m_r[r] - mn);
            m_r[r] = mn;
            float p0 = __expf(sv0 - mn), p1 = __expf(sv1 - mn);
            float p2 = __expf(sv2 - mn), p3 = __expf(sv3 - mn);
            pv[0][r] = p0; pv[1][r] = p1; pv[2][r] = p2; pv[3][r] = p3;
            float ps = (p0 + p1) + (p2 + p3);
            ps += __shfl_xor(ps, 1);
            ps += __shfl_xor(ps, 2);
            ps += __shfl_xor(ps, 4);
            ps += __shfl_xor(ps, 8);
            l_r[r] = l_r[r] * corr + ps;
            #pragma unroll
            for (int dg = 0; dg < 4; ++dg) acc[dg][r] *= corr;
        }

        // P -> LDS, read back as A-frag
        #pragma unroll
        for (int kg = 0; kg < 4; ++kg)
            #pragma unroll
            for (int r = 0; r < 4; ++r)
                Ps[wv][rg * 4 + r][kg * 16 + lr] = f2bf(pv[kg][r]);

        // PV
        #pragma unroll
        for (int kk = 0; kk < 2; ++kk) {
            bt8 pa = *(const bt8*)&Ps[wv][lr][kk * 32 + lk];
            #pragma unroll
            for (int dg = 0; dg < 4; ++dg) {
                bt8 vf2 = *(const bt8*)&Vt[dg * 16 + lr][kk * 32 + lk];
                acc[dg] = __builtin_amdgcn_mfma_f32_16x16x32_bf16(pa, vf2, acc[dg], 0, 0, 0);
            }
        }
    }

    // write partials
    if (lr == 0) {
        #pragma unroll
        for (int r = 0; r < 4; ++r) {
            int qi = q0 + rg * 4 + r;
            int prow = (bh * nspl + spl) * qrows + qi;
            Mo[prow] = m_r[r];
            Lo[prow] = l_r[r];
        }
    }
    #pragma unroll
    for (int r = 0; r < 4; ++r) {
        int qi = q0 + rg * 4 + r;
        size_t orow = ((size_t)(bh * nspl + spl) * qrows + qi) * 64;
        #pragma unroll
        for (int dg = 0; dg < 4; ++dg)
            Oo[orow + dg * 16 + lr] = f2bf(acc[dg][r]);
    }
}

// ---------------- merge split partials -> psi (bf16), optional strided f32 residual
__global__ __launch_bounds__(64) void attn_merge(
    const float* __restrict__ Mo, const float* __restrict__ Lo, const ushort* __restrict__ Oo,
    const float* __restrict__ resid, size_t rbstride, int rstride,
    ushort* __restrict__ psi,
    int nspl, int qrows, int qmax, int out_rows)
{
    const int tid = threadIdx.x, bh = blockIdx.x, qb = blockIdx.y;
    const int b = bh / 12, h = bh % 12;
    const int qi = qb * 64 + tid;
    if (qi >= qmax) return;
    const int pb = bh * nspl;

    float M = -3.0e38f;
    for (int s = 0; s < nspl; ++s)
        M = fmaxf(M, Mo[(pb + s) * qrows + qi]);
    float L = 0.f, O[64];
    #pragma unroll
    for (int d = 0; d < 64; ++d) O[d] = 0.f;
    for (int s = 0; s < nspl; ++s) {
        int pr = (pb + s) * qrows + qi;
        float f = __expf(Mo[pr] - M);
        L += Lo[pr] * f;
        const uint* op = (const uint*)(Oo + (size_t)pr * 64);
        #pragma unroll
        for (int d2 = 0; d2 < 32; ++d2) {
            uint u = op[d2];
            O[2*d2]   += f * bf2f((ushort)(u & 0xffffu));
            O[2*d2+1] += f * bf2f((ushort)(u >> 16));
        }
    }
    const float rl = 1.f / L;
    const size_t ob = ((size_t)b * out_rows + qi) * 768 + h * 64;
    if (resid) {
        const float* rp = resid + (size_t)b * rbstride + (size_t)qi * rstride + h * 64;
        #pragma unroll
        for (int d = 0; d < 64; ++d)
            psi[ob + d] = f2bf(O[d] * rl + rp[d]);
    } else {
        #pragma unroll
        for (int d = 0; d < 64; ++d)
            psi[ob + d] = f2bf(O[d] * rl);
    }
}

// ---------------- LayerNorm( gin + residual ) * g + b  -> f32 out
__global__ __launch_bounds__(256) void ln_ker(
    const float* __restrict__ gin, const float* __restrict__ resid,
    const float* __restrict__ g, const float* __restrict__ bta,
    float* __restrict__ out)
{
    const int row = blockIdx.x, tid = threadIdx.x;
    const size_t rb = (size_t)row * 768;
    float x[3], s = 0.f, s2 = 0.f;
    #pragma unroll
    for (int k2 = 0; k2 < 3; ++k2) {
        int c = k2 * 256 + tid;
        float v = gin[rb + c] + resid[rb + c];
        x[k2] = v; s += v; s2 += v * v;
    }
    #pragma unroll
    for (int off = 32; off > 0; off >>= 1) {
        s  += __shfl_down(s, off);
        s2 += __shfl_down(s2, off);
    }
    __shared__ float red[10];
    const int wv = tid >> 6;
    if ((tid & 63) == 0) { red[wv] = s; red[4 + wv] = s2; }
    __syncthreads();
    if (tid == 0) {
        float ts = red[0] + red[1] + red[2] + red[3];
        float t2 = red[4] + red[5] + red[6] + red[7];
        float mean = ts * (1.f / 768.f);
        float var = t2 * (1.f / 768.f) - mean * mean;
        red[8] = mean;
        red[9] = rsqrtf(fmaxf(var, 0.f) + 1e-6f);
    }
    __syncthreads();
    const float mean = red[8], rstd = red[9];
    #pragma unroll
    for (int k2 = 0; k2 < 3; ++k2) {
        int c = k2 * 256 + tid;
        out[rb + c] = (x[k2] - mean) * rstd * g[c] + bta[c];
    }
}

extern "C" void kernel_launch(void* const* d_in, const int* in_sizes, int n_in,
                              void* d_out, int out_size, void* d_ws, size_t ws_size,
                              hipStream_t stream) {
    const float* doc  = (const float*)d_in[0];
    const float* rel  = (const float*)d_in[1];
    const int*   mask = (const int*)d_in[2];
    const float* wq_doc = (const float*)d_in[3];
    const float* wk_doc = (const float*)d_in[4];
    const float* wv_doc = (const float*)d_in[5];
    const float* wk_rel = (const float*)d_in[6];
    const float* wv_rel = (const float*)d_in[7];
    const float* fc_doc = (const float*)d_in[8];
    const float* fc_rel = (const float*)d_in[9];
    const float* ln_dg = (const float*)d_in[10];
    const float* ln_db = (const float*)d_in[11];
    const float* ln_rg = (const float*)d_in[12];
    const float* ln_rb = (const float*)d_in[13];

    char* ws = (char*)d_ws;
    size_t off = 0;
    ushort* wtqkv = (ushort*)(ws + off); off += (size_t)2304 * 768 * 2;  // [2304][768]
    ushort* wt34  = (ushort*)(ws + off); off += (size_t)1536 * 768 * 2;  // [1536][768]
    ushort* wt5   = (ushort*)(ws + off); off += (size_t)768 * 768 * 2;
    ushort* wt6   = (ushort*)(ws + off); off += (size_t)768 * 768 * 2;
    ushort* doc_bf = (ushort*)(ws + off); off += (size_t)4096 * 768 * 2;
    ushort* rel_bf = (ushort*)(ws + off); off += (size_t)388 * 768 * 2;
    ushort* qkv_bf = (ushort*)(ws + off); off += (size_t)4096 * 2304 * 2; // [4096][2304]
    float*  rkvb   = (float*)(ws + off);  off += (size_t)388 * 1536 * 4;  // [388][1536] f32
    ushort* rkv_bf = (ushort*)(ws + off); off += (size_t)388 * 1536 * 2;
    float*  rks = (float*)(ws + off); off += (size_t)4 * 768 * 4;
    float*  rvs = (float*)(ws + off); off += (size_t)4 * 768 * 4;
    ushort* kf_bf = (ushort*)(ws + off); off += (size_t)4096 * 768 * 2;
    ushort* vf_bf = (ushort*)(ws + off); off += (size_t)4096 * 768 * 2;
    ushort* psi_i = (ushort*)(ws + off); off += (size_t)4096 * 768 * 2;
    ushort* psi_r = (ushort*)(ws + off); off += (size_t)388 * 768 * 2;
    float*  Mo = (float*)(ws + off);  off += (size_t)48 * 2 * 1024 * 4;
    float*  Lo = (float*)(ws + off);  off += (size_t)48 * 2 * 1024 * 4;
    ushort* Oo = (ushort*)(ws + off); off += (size_t)48 * 2 * 1024 * 64 * 2;
    float*  gdoc = (float*)(ws + off); off += (size_t)4096 * 768 * 4;
    float*  grel = (float*)(ws + off); off += (size_t)388 * 768 * 4;

    float* out_doc = (float*)d_out;
    float* out_rel = out_doc + (size_t)4096 * 768;

    // input converts
    cvt_bf16<<<dim3((4096 * 768 + 255) / 256), 256, 0, stream>>>(doc, doc_bf, 4096 * 768);
    cvt_bf16<<<dim3((388 * 768 + 255) / 256), 256, 0, stream>>>(rel, rel_bf, 388 * 768);
    // weight transposes into fused layouts
    transpose768<<<dim3(24, 24), dim3(32, 8), 0, stream>>>(wq_doc, wtqkv);
    transpose768<<<dim3(24, 24), dim3(32, 8), 0, stream>>>(wk_doc, wtqkv + (size_t)768 * 768);
    transpose768<<<dim3(24, 24), dim3(32, 8), 0, stream>>>(wv_doc, wtqkv + (size_t)2 * 768 * 768);
    transpose768<<<dim3(24, 24), dim3(32, 8), 0, stream>>>(wk_rel, wt34);
    transpose768<<<dim3(24, 24), dim3(32, 8), 0, stream>>>(wv_rel, wt34 + (size_t)768 * 768);
    transpose768<<<dim3(24, 24), dim3(32, 8), 0, stream>>>(fc_doc, wt5);
    transpose768<<<dim3(24, 24), dim3(32, 8), 0, stream>>>(fc_rel, wt6);

    // fused projections
    gemm_t<128, 128, 2, 4, 4, true><<<dim3(32, 18), 256, 0, stream>>>(
        doc_bf, wtqkv, qkv_bf, 4096, 2304, 768);
    gemm_t<128, 128, 2, 4, 4, false><<<dim3(4, 12), 256, 0, stream>>>(
        rel_bf, wt34, rkvb, 388, 1536, 768);
    cvt_bf16<<<dim3((388 * 1536 + 255) / 256), 256, 0, stream>>>(rkvb, rkv_bf, 388 * 1536);

    // relation sums + fused K/V (bf16)
    relsum<<<dim3(4, 3), 256, 0, stream>>>(rkvb, rks, rvs);
    fusekv<<<dim3(4096, 3), 256, 0, stream>>>(qkv_bf, rks, rvs, kf_bf, vf_bf);

    // rel-doc attention on RAW k/v (qkv slices): 8 splits x 2 tiles
    attn_mfma<<<dim3(48, 2, 8), 256, 0, stream>>>(
        rkv_bf, 1536, (size_t)97 * 1536, 97,
        qkv_bf + 768, qkv_bf + 1536, 2304, (size_t)1024 * 2304,
        mask, Mo, Lo, Oo, 8, 2, 128);
    attn_merge<<<dim3(48, 2), 64, 0, stream>>>(
        Mo, Lo, Oo, rkvb + 768, (size_t)97 * 1536, 1536, psi_r, 8, 128, 97, 97);

    // doc-doc attention on fused K/V: 2 splits x 8 tiles
    attn_mfma<<<dim3(48, 16, 2), 256, 0, stream>>>(
        qkv_bf, 2304, (size_t)1024 * 2304, 1024,
        kf_bf, vf_bf, 768, (size_t)1024 * 768,
        mask, Mo, Lo, Oo, 2, 8, 1024);
    attn_merge<<<dim3(48, 16), 64, 0, stream>>>(
        Mo, Lo, Oo, (const float*)nullptr, 0, 0, psi_i, 2, 1024, 1024, 1024);

    // output projections (BM=64 config for better fill at N=768)
    gemm_t<64, 128, 4, 4, 2, false><<<dim3(64, 6), 256, 0, stream>>>(
        psi_i, wt5, gdoc, 4096, 768, 768);
    gemm_t<64, 128, 4, 4, 2, false><<<dim3(7, 6), 256, 0, stream>>>(
        psi_r, wt6, grel, 388, 768, 768);

    // layernorm + residual -> f32 outputs
    ln_ker<<<4096, 256, 0, stream>>>(gdoc, doc, ln_dg, ln_db, out_doc);
    ln_ker<<<388,  256, 0, stream>>>(grel, rel, ln_rg, ln_rb, out_rel);
}

// Round 8
// 216.252 us; speedup vs baseline: 8.9871x; 1.2271x over previous
//
#include <hip/hip_runtime.h>

typedef __attribute__((ext_vector_type(8))) short bt8;   // 8 bf16 (4 VGPR)
typedef __attribute__((ext_vector_type(4))) float f32x4; // 4 f32

__device__ __forceinline__ float bf2f(ushort u) {
    union { unsigned int i; float f; } v; v.i = ((unsigned int)u) << 16; return v.f;
}
__device__ __forceinline__ ushort f2bf(float f) {
    union { float f; unsigned int i; } v; v.f = f;
    unsigned int r = v.i + 0x7fffu + ((v.i >> 16) & 1u);
    return (ushort)(r >> 16);
}

#define GLOAD_LDS16(gp, lp) __builtin_amdgcn_global_load_lds( \
    (const __attribute__((address_space(1))) unsigned int*)(gp), \
    (__attribute__((address_space(3))) unsigned int*)(lp), 16, 0, 0)

// ---------------- f32 -> bf16 elementwise convert
__global__ __launch_bounds__(256) void cvt_bf16(const float* __restrict__ in,
                                                ushort* __restrict__ out, int n) {
    int i = blockIdx.x * 256 + threadIdx.x;
    if (i < n) out[i] = f2bf(in[i]);
}

// ---------------- batched weight transpose+convert: 7x W[768,768] f32 -> WT bf16 (out,in)
__global__ void transpose_all(const float* __restrict__ p0, const float* __restrict__ p1,
                              const float* __restrict__ p2, const float* __restrict__ p3,
                              const float* __restrict__ p4, const float* __restrict__ p5,
                              const float* __restrict__ p6, ushort* __restrict__ out) {
    __shared__ float t[32][33];
    const float* W;
    switch (blockIdx.z) {
        case 0: W = p0; break; case 1: W = p1; break; case 2: W = p2; break;
        case 3: W = p3; break; case 4: W = p4; break; case 5: W = p5; break;
        default: W = p6; break;
    }
    ushort* WT = out + (size_t)blockIdx.z * 768 * 768;
    int bx = blockIdx.x * 32, by = blockIdx.y * 32;
    int x = threadIdx.x, y0 = threadIdx.y;
    for (int y = y0; y < 32; y += 8)
        t[y][x] = W[(size_t)(by + y) * 768 + bx + x];
    __syncthreads();
    for (int y = y0; y < 32; y += 8)
        WT[(size_t)(bx + y) * 768 + by + x] = f2bf(t[x][y]);
}

// ---------------- m97-style MFMA GEMM: global_load_lds width-16, linear LDS
// C[M,N] = A[M,K] @ BT[N,K]^T ; 128x128 tile, BK=32, 4 waves.
// A rows clamped to M-1 (surplus rows compute garbage, never stored).
template<bool BF16O>
__global__ __launch_bounds__(256) void gemm_gl(
    const ushort* __restrict__ A, const ushort* __restrict__ BT,
    void* __restrict__ Cv, int M, int N, int K)
{
    __shared__ ushort As[128 * 32];
    __shared__ ushort Bs[128 * 32];
    const int tid = threadIdx.x;
    const int wave = tid >> 6, lane = tid & 63;
    const int row0 = blockIdx.x * 128, col0 = blockIdx.y * 128;
    const int wm = (wave >> 1) * 64, wn = (wave & 1) * 64;
    const int lr = lane & 15, lk = (lane >> 4) * 8;
    const int srow = wave * 16 + (lane >> 2);   // staging row within 64-row chunk
    const int scol = (lane & 3) * 8;            // staging col (hw)

    f32x4 acc[4][4];
    #pragma unroll
    for (int mi = 0; mi < 4; ++mi)
        #pragma unroll
        for (int ni = 0; ni < 4; ++ni)
            acc[mi][ni] = (f32x4){0.f, 0.f, 0.f, 0.f};

    // per-lane clamped A rows (valid data always; rows >= M duplicate M-1)
    int ar0 = row0 + srow;       if (ar0 >= M) ar0 = M - 1;
    int ar1 = row0 + 64 + srow;  if (ar1 >= M) ar1 = M - 1;
    const int bc0 = col0 + srow, bc1 = col0 + 64 + srow;

    for (int kt = 0; kt < K; kt += 32) {
        __syncthreads();
        GLOAD_LDS16(A + (size_t)ar0 * K + kt + scol, As + wave * 512);
        GLOAD_LDS16(A + (size_t)ar1 * K + kt + scol, As + 2048 + wave * 512);
        GLOAD_LDS16(BT + (size_t)bc0 * K + kt + scol, Bs + wave * 512);
        GLOAD_LDS16(BT + (size_t)bc1 * K + kt + scol, Bs + 2048 + wave * 512);
        __syncthreads();
        bt8 af[4], bf[4];
        #pragma unroll
        for (int mi = 0; mi < 4; ++mi)
            af[mi] = *(const bt8*)&As[(wm + mi * 16 + lr) * 32 + lk];
        #pragma unroll
        for (int ni = 0; ni < 4; ++ni)
            bf[ni] = *(const bt8*)&Bs[(wn + ni * 16 + lr) * 32 + lk];
        #pragma unroll
        for (int mi = 0; mi < 4; ++mi)
            #pragma unroll
            for (int ni = 0; ni < 4; ++ni)
                acc[mi][ni] = __builtin_amdgcn_mfma_f32_16x16x32_bf16(
                    af[mi], bf[ni], acc[mi][ni], 0, 0, 0);
    }

    #pragma unroll
    for (int mi = 0; mi < 4; ++mi) {
        int orow0 = row0 + wm + mi * 16 + (lane >> 4) * 4;
        #pragma unroll
        for (int ni = 0; ni < 4; ++ni) {
            int ocol = col0 + wn + ni * 16 + lr;
            if (ocol >= N) continue;
            #pragma unroll
            for (int r2 = 0; r2 < 4; ++r2) {
                int orow = orow0 + r2;
                if (orow < M) {
                    if (BF16O)
                        ((ushort*)Cv)[(size_t)orow * N + ocol] = f2bf(acc[mi][ni][r2]);
                    else
                        ((float*)Cv)[(size_t)orow * N + ocol] = acc[mi][ni][r2];
                }
            }
        }
    }
}

// ---------------- per-(b) column sums of rel K/V from fused rkv (bf16, stride 1536)
__global__ void relsum(const ushort* __restrict__ rkv,
                       float* __restrict__ rks, float* __restrict__ rvs) {
    int b = blockIdx.x;
    int c = blockIdx.y * 256 + threadIdx.x;  // 0..767
    float s1 = 0.f, s2 = 0.f;
    for (int r = 0; r < 97; ++r) {
        const ushort* row = rkv + (size_t)(b * 97 + r) * 1536;
        s1 += bf2f(row[c]);
        s2 += bf2f(row[768 + c]);
    }
    rks[b * 768 + c] = s1;
    rvs[b * 768 + c] = s2;
}

// ---------------- fused_k/fused_v (bf16): kf = k + rks[b], vf = v + rvs[b]
__global__ __launch_bounds__(256) void fusekv(
    const ushort* __restrict__ qkv, const float* __restrict__ rks,
    const float* __restrict__ rvs, ushort* __restrict__ kf, ushort* __restrict__ vf)
{
    int row = blockIdx.x;                       // 0..4095
    int c = blockIdx.y * 256 + threadIdx.x;     // 0..767
    int b = row >> 10;
    size_t qi = (size_t)row * 2304;
    size_t oi = (size_t)row * 768 + c;
    kf[oi] = f2bf(bf2f(qkv[qi + 768 + c]) + rks[b * 768 + c]);
    vf[oi] = f2bf(bf2f(qkv[qi + 1536 + c]) + rvs[b * 768 + c]);
}

// ---------------- MFMA flash attention partial (split-K), bf16 in, XOR-swizzled LDS
// Block: 256 thr = 4 waves, each wave owns 16 q-rows (block = 64 q-rows).
__global__ __launch_bounds__(256) void attn_mfma(
    const ushort* __restrict__ Qp, int qstride, size_t qbstride, int qmax,
    const ushort* __restrict__ Kp, const ushort* __restrict__ Vp,
    int kvstride, size_t kvbstride,
    const int* __restrict__ mask,
    float* __restrict__ Mo, float* __restrict__ Lo, ushort* __restrict__ Oo,
    int nspl, int ntiles, int qrows)
{
    __shared__ ushort Ks[64 * 64];      // [key][k], hw ^= (key&7)<<3
    __shared__ ushort Vt[64 * 64];      // [d][key], hw ^= (d&7)<<3
    __shared__ ushort Ps[4][16 * 64];   // per-wave [qrow][key], hw ^= (qrow&7)<<3
    __shared__ float  madd[64];

    const int tid = threadIdx.x;
    const int wv = tid >> 6, lane = tid & 63;
    const int lr = lane & 15, lk = (lane >> 4) * 8, rg = lane >> 4;
    const int bh = blockIdx.x, b = bh / 12, h = bh % 12;
    const int qb = blockIdx.y, spl = blockIdx.z;
    const int q0 = qb * 64 + wv * 16;

    const size_t kvbase = (size_t)b * kvbstride + h * 64;
    const size_t qbase  = (size_t)b * qbstride + h * 64;

    // Q fragments (bf16 direct)
    bt8 qf[2];
    {
        const int qi = q0 + lr;
        if (qi < qmax) {
            const ushort* qp = Qp + qbase + (size_t)qi * qstride + lk;
            qf[0] = *(const bt8*)qp;
            qf[1] = *(const bt8*)(qp + 32);
        } else {
            #pragma unroll
            for (int j = 0; j < 8; ++j) { qf[0][j] = 0; qf[1][j] = 0; }
        }
    }

    f32x4 acc[4];
    #pragma unroll
    for (int dg = 0; dg < 4; ++dg) acc[dg] = (f32x4){0.f, 0.f, 0.f, 0.f};
    float m_r[4], l_r[4];
    #pragma unroll
    for (int r = 0; r < 4; ++r) { m_r[r] = -3.0e38f; l_r[r] = 0.f; }

    const int key = tid >> 2, c0 = (tid & 3) * 16;  // K staging
    const int vd = tid & 63, vw = tid >> 6;         // V staging (column gather)
    const int swk = (key & 7) << 3;
    const int swv = (vd & 7) << 3;
    const int swl = (lr & 7) << 3;                  // swizzle for frag reads

    for (int t = 0; t < ntiles; ++t) {
        const int k0 = (spl * ntiles + t) * 64;
        __syncthreads();
        // stage K tile: 2 b128 swizzled writes
        {
            const ushort* src = Kp + kvbase + (size_t)(k0 + key) * kvstride + c0;
            int4 a = *(const int4*)src;
            int4 bq = *(const int4*)(src + 8);
            *(int4*)&Ks[key * 64 + (c0 ^ swk)] = a;
            *(int4*)&Ks[key * 64 + ((c0 + 8) ^ swk)] = bq;
        }
        // stage V transposed: gather d-column of 16 keys, 2 b128 swizzled writes
        {
            const ushort* vsrc = Vp + kvbase + (size_t)(k0 + vw * 16) * kvstride + vd;
            ushort tv[16];
            #pragma unroll
            for (int j = 0; j < 16; ++j) tv[j] = vsrc[(size_t)j * kvstride];
            const int cc = vw * 16;
            *(int4*)&Vt[vd * 64 + (cc ^ swv)] = *(int4*)tv;
            *(int4*)&Vt[vd * 64 + ((cc + 8) ^ swv)] = *(int4*)(tv + 8);
        }
        if (tid < 64)
            madd[tid] = (mask[b * 1024 + k0 + tid] == 0) ? -1e30f : 0.f;
        __syncthreads();

        // S = Q K^T (swizzled Ks reads)
        f32x4 sf[4];
        #pragma unroll
        for (int kg = 0; kg < 4; ++kg) {
            f32x4 s4 = (f32x4){0.f, 0.f, 0.f, 0.f};
            #pragma unroll
            for (int kk = 0; kk < 2; ++kk) {
                bt8 kf2 = *(const bt8*)&Ks[(kg * 16 + lr) * 64 + ((kk * 32 + lk) ^ swl)];
                s4 = __builtin_amdgcn_mfma_f32_16x16x32_bf16(qf[kk], kf2, s4, 0, 0, 0);
            }
            sf[kg] = s4;
        }

        // online softmax (per reg r = qrow)
        float pv[4][4];
        #pragma unroll
        for (int r = 0; r < 4; ++r) {
            float sv0 = sf[0][r] * 0.125f + madd[lr];
            float sv1 = sf[1][r] * 0.125f + madd[16 + lr];
            float sv2 = sf[2][r] * 0.125f + madd[32 + lr];
            float sv3 = sf[3][r] * 0.125f + madd[48 + lr];
            float mx = fmaxf(fmaxf(sv0, sv1), fmaxf(sv2, sv3));
            mx = fmaxf(mx, __shfl_xor(mx, 1));
            mx = fmaxf(mx, __shfl_xor(mx, 2));
            mx = fmaxf(mx, __shfl_xor(mx, 4));
            mx = fmaxf(mx, __shfl_xor(mx, 8));
            float mn = fmaxf(m_r[r], mx);
            float corr = __expf(m_r[r] - mn);
            m_r[r] = mn;
            float p0 = __expf(sv0 - mn), p1 = __expf(sv1 - mn);
            float p2 = __expf(sv2 - mn), p3 = __expf(sv3 - mn);
            pv[0][r] = p0; pv[1][r] = p1; pv[2][r] = p2; pv[3][r] = p3;
            float ps = (p0 + p1) + (p2 + p3);
            ps += __shfl_xor(ps, 1);
            ps += __shfl_xor(ps, 2);
            ps += __shfl_xor(ps, 4);
            ps += __shfl_xor(ps, 8);
            l_r[r] = l_r[r] * corr + ps;
            #pragma unroll
            for (int dg = 0; dg < 4; ++dg) acc[dg][r] *= corr;
        }

        // P -> per-wave LDS (swizzled b16 scatter), read back as A-frag
        #pragma unroll
        for (int kg = 0; kg < 4; ++kg)
            #pragma unroll
            for (int r = 0; r < 4; ++r) {
                int rowq = rg * 4 + r;
                Ps[wv][rowq * 64 + ((kg * 16 + lr) ^ ((rowq & 7) << 3))] = f2bf(pv[kg][r]);
            }

        // PV (swizzled Ps / Vt reads)
        #pragma unroll
        for (int kk = 0; kk < 2; ++kk) {
            bt8 pa = *(const bt8*)&Ps[wv][lr * 64 + ((kk * 32 + lk) ^ swl)];
            #pragma unroll
            for (int dg = 0; dg < 4; ++dg) {
                bt8 vf2 = *(const bt8*)&Vt[(dg * 16 + lr) * 64 + ((kk * 32 + lk) ^ swl)];
                acc[dg] = __builtin_amdgcn_mfma_f32_16x16x32_bf16(pa, vf2, acc[dg], 0, 0, 0);
            }
        }
    }

    // write partials
    if (lr == 0) {
        #pragma unroll
        for (int r = 0; r < 4; ++r) {
            int qi = q0 + rg * 4 + r;
            int prow = (bh * nspl + spl) * qrows + qi;
            Mo[prow] = m_r[r];
            Lo[prow] = l_r[r];
        }
    }
    #pragma unroll
    for (int r = 0; r < 4; ++r) {
        int qi = q0 + rg * 4 + r;
        size_t orow = ((size_t)(bh * nspl + spl) * qrows + qi) * 64;
        #pragma unroll
        for (int dg = 0; dg < 4; ++dg)
            Oo[orow + dg * 16 + lr] = f2bf(acc[dg][r]);
    }
}

// ---------------- merge split partials -> psi (bf16), optional bf16 strided residual
__global__ __launch_bounds__(64) void attn_merge(
    const float* __restrict__ Mo, const float* __restrict__ Lo, const ushort* __restrict__ Oo,
    const ushort* __restrict__ resid, size_t rbstride, int rstride,
    ushort* __restrict__ psi,
    int nspl, int qrows, int qmax, int out_rows)
{
    const int tid = threadIdx.x, bh = blockIdx.x, qb = blockIdx.y;
    const int b = bh / 12, h = bh % 12;
    const int qi = qb * 64 + tid;
    if (qi >= qmax) return;
    const int pb = bh * nspl;

    float M = -3.0e38f;
    for (int s = 0; s < nspl; ++s)
        M = fmaxf(M, Mo[(pb + s) * qrows + qi]);
    float L = 0.f, O[64];
    #pragma unroll
    for (int d = 0; d < 64; ++d) O[d] = 0.f;
    for (int s = 0; s < nspl; ++s) {
        int pr = (pb + s) * qrows + qi;
        float f = __expf(Mo[pr] - M);
        L += Lo[pr] * f;
        const uint* op = (const uint*)(Oo + (size_t)pr * 64);
        #pragma unroll
        for (int d2 = 0; d2 < 32; ++d2) {
            uint u = op[d2];
            O[2*d2]   += f * bf2f((ushort)(u & 0xffffu));
            O[2*d2+1] += f * bf2f((ushort)(u >> 16));
        }
    }
    const float rl = 1.f / L;
    const size_t ob = ((size_t)b * out_rows + qi) * 768 + h * 64;
    if (resid) {
        const ushort* rp = resid + (size_t)b * rbstride + (size_t)qi * rstride + h * 64;
        #pragma unroll
        for (int d = 0; d < 64; ++d)
            psi[ob + d] = f2bf(O[d] * rl + bf2f(rp[d]));
    } else {
        #pragma unroll
        for (int d = 0; d < 64; ++d)
            psi[ob + d] = f2bf(O[d] * rl);
    }
}

// ---------------- LayerNorm( gin + residual ) * g + b  -> f32 out
__global__ __launch_bounds__(256) void ln_ker(
    const float* __restrict__ gin, const float* __restrict__ resid,
    const float* __restrict__ g, const float* __restrict__ bta,
    float* __restrict__ out)
{
    const int row = blockIdx.x, tid = threadIdx.x;
    const size_t rb = (size_t)row * 768;
    float x[3], s = 0.f, s2 = 0.f;
    #pragma unroll
    for (int k2 = 0; k2 < 3; ++k2) {
        int c = k2 * 256 + tid;
        float v = gin[rb + c] + resid[rb + c];
        x[k2] = v; s += v; s2 += v * v;
    }
    #pragma unroll
    for (int off = 32; off > 0; off >>= 1) {
        s  += __shfl_down(s, off);
        s2 += __shfl_down(s2, off);
    }
    __shared__ float red[10];
    const int wv = tid >> 6;
    if ((tid & 63) == 0) { red[wv] = s; red[4 + wv] = s2; }
    __syncthreads();
    if (tid == 0) {
        float ts = red[0] + red[1] + red[2] + red[3];
        float t2 = red[4] + red[5] + red[6] + red[7];
        float mean = ts * (1.f / 768.f);
        float var = t2 * (1.f / 768.f) - mean * mean;
        red[8] = mean;
        red[9] = rsqrtf(fmaxf(var, 0.f) + 1e-6f);
    }
    __syncthreads();
    const float mean = red[8], rstd = red[9];
    #pragma unroll
    for (int k2 = 0; k2 < 3; ++k2) {
        int c = k2 * 256 + tid;
        out[rb + c] = (x[k2] - mean) * rstd * g[c] + bta[c];
    }
}

extern "C" void kernel_launch(void* const* d_in, const int* in_sizes, int n_in,
                              void* d_out, int out_size, void* d_ws, size_t ws_size,
                              hipStream_t stream) {
    const float* doc  = (const float*)d_in[0];
    const float* rel  = (const float*)d_in[1];
    const int*   mask = (const int*)d_in[2];
    const float* ln_dg = (const float*)d_in[10];
    const float* ln_db = (const float*)d_in[11];
    const float* ln_rg = (const float*)d_in[12];
    const float* ln_rb = (const float*)d_in[13];

    char* ws = (char*)d_ws;
    size_t off = 0;
    // batched transposed weights: [wq | wk | wv | wk_rel | wv_rel | fc_doc | fc_rel]
    ushort* wtall = (ushort*)(ws + off); off += (size_t)7 * 768 * 768 * 2;
    ushort* wtqkv = wtall;                        // [2304][768]
    ushort* wt34  = wtall + (size_t)3 * 768 * 768; // [1536][768]
    ushort* wt5   = wtall + (size_t)5 * 768 * 768;
    ushort* wt6   = wtall + (size_t)6 * 768 * 768;
    ushort* doc_bf = (ushort*)(ws + off); off += (size_t)4096 * 768 * 2;
    ushort* rel_bf = (ushort*)(ws + off); off += (size_t)388 * 768 * 2;
    ushort* qkv_bf = (ushort*)(ws + off); off += (size_t)4096 * 2304 * 2; // [4096][2304]
    ushort* rkv_bf = (ushort*)(ws + off); off += (size_t)388 * 1536 * 2;  // [388][1536]
    float*  rks = (float*)(ws + off); off += (size_t)4 * 768 * 4;
    float*  rvs = (float*)(ws + off); off += (size_t)4 * 768 * 4;
    ushort* kf_bf = (ushort*)(ws + off); off += (size_t)4096 * 768 * 2;
    ushort* vf_bf = (ushort*)(ws + off); off += (size_t)4096 * 768 * 2;
    ushort* psi_i = (ushort*)(ws + off); off += (size_t)4096 * 768 * 2;
    ushort* psi_r = (ushort*)(ws + off); off += (size_t)388 * 768 * 2;
    float*  Mo = (float*)(ws + off);  off += (size_t)48 * 2 * 1024 * 4;
    float*  Lo = (float*)(ws + off);  off += (size_t)48 * 2 * 1024 * 4;
    ushort* Oo = (ushort*)(ws + off); off += (size_t)48 * 2 * 1024 * 64 * 2;
    float*  gdoc = (float*)(ws + off); off += (size_t)4096 * 768 * 4;
    float*  grel = (float*)(ws + off); off += (size_t)388 * 768 * 4;

    float* out_doc = (float*)d_out;
    float* out_rel = out_doc + (size_t)4096 * 768;

    // input converts + batched weight transpose
    cvt_bf16<<<dim3((4096 * 768 + 255) / 256), 256, 0, stream>>>(doc, doc_bf, 4096 * 768);
    cvt_bf16<<<dim3((388 * 768 + 255) / 256), 256, 0, stream>>>(rel, rel_bf, 388 * 768);
    transpose_all<<<dim3(24, 24, 7), dim3(32, 8), 0, stream>>>(
        (const float*)d_in[3], (const float*)d_in[4], (const float*)d_in[5],
        (const float*)d_in[6], (const float*)d_in[7], (const float*)d_in[8],
        (const float*)d_in[9], wtall);

    // fused projections (bf16 out)
    gemm_gl<true><<<dim3(32, 18), 256, 0, stream>>>(doc_bf, wtqkv, qkv_bf, 4096, 2304, 768);
    gemm_gl<true><<<dim3(4, 12),  256, 0, stream>>>(rel_bf, wt34, rkv_bf, 388, 1536, 768);

    // relation sums + fused K/V (bf16)
    relsum<<<dim3(4, 3), 256, 0, stream>>>(rkv_bf, rks, rvs);
    fusekv<<<dim3(4096, 3), 256, 0, stream>>>(qkv_bf, rks, rvs, kf_bf, vf_bf);

    // rel-doc attention on RAW k/v (qkv slices): 8 splits x 2 tiles
    attn_mfma<<<dim3(48, 2, 8), 256, 0, stream>>>(
        rkv_bf, 1536, (size_t)97 * 1536, 97,
        qkv_bf + 768, qkv_bf + 1536, 2304, (size_t)1024 * 2304,
        mask, Mo, Lo, Oo, 8, 2, 128);
    attn_merge<<<dim3(48, 2), 64, 0, stream>>>(
        Mo, Lo, Oo, rkv_bf + 768, (size_t)97 * 1536, 1536, psi_r, 8, 128, 97, 97);

    // doc-doc attention on fused K/V: 2 splits x 8 tiles
    attn_mfma<<<dim3(48, 16, 2), 256, 0, stream>>>(
        qkv_bf, 2304, (size_t)1024 * 2304, 1024,
        kf_bf, vf_bf, 768, (size_t)1024 * 768,
        mask, Mo, Lo, Oo, 2, 8, 1024);
    attn_merge<<<dim3(48, 16), 64, 0, stream>>>(
        Mo, Lo, Oo, (const ushort*)nullptr, 0, 0, psi_i, 2, 1024, 1024, 1024);

    // output projections
    gemm_gl<false><<<dim3(32, 6), 256, 0, stream>>>(psi_i, wt5, gdoc, 4096, 768, 768);
    gemm_gl<false><<<dim3(4, 6),  256, 0, stream>>>(psi_r, wt6, grel, 388, 768, 768);

    // layernorm + residual -> f32 outputs
    ln_ker<<<4096, 256, 0, stream>>>(gdoc, doc, ln_dg, ln_db, out_doc);
    ln_ker<<<388,  256, 0, stream>>>(grel, rel, ln_rg, ln_rb, out_rel);
}